// Round 1
// baseline (1592.203 us; speedup 1.0000x reference)
//
#include <hip/hip_runtime.h>

#define NCC 617
#define TTT 15
#define FFF 5
#define SSN 200000
#define EEN 1000000
#define ECN 20000
#define CSBLK 196   /* ceil(SSN/1024) */

typedef unsigned short u16;
typedef unsigned int   u32;

__device__ __forceinline__ float bf2f(u16 u){ return __uint_as_float(((u32)u) << 16); }
__device__ __forceinline__ u16 f2bf(float f){
  u32 x = __float_as_uint(f);
  u32 r = (x + 0x7fffu + ((x >> 16) & 1u)) >> 16;
  return (u16)r;
}
__device__ __forceinline__ float sigm(float x){ return 1.0f / (1.0f + __expf(-x)); }

// ---------------- utility kernels ----------------
__global__ __launch_bounds__(256) void k_zero(int* p, int n){
  int i = blockIdx.x * 256 + threadIdx.x;
  if (i < n) p[i] = 0;
}
__global__ __launch_bounds__(256) void k_copy(const int* a, int* b, int n){
  int i = blockIdx.x * 256 + threadIdx.x;
  if (i < n) b[i] = a[i];
}
__global__ __launch_bounds__(256) void k_hist(const int* dst, int n, int* cnt){
  int i = blockIdx.x * 256 + threadIdx.x;
  if (i < n) atomicAdd(&cnt[dst[i]], 1);
}
__global__ __launch_bounds__(256) void k_scatter(const int* src, const int* dst, int n, int* cur, int* bkt){
  int i = blockIdx.x * 256 + threadIdx.x;
  if (i < n){ int p = atomicAdd(&cur[dst[i]], 1); bkt[p] = src[i]; }
}

// exclusive scan for n <= 1024, writes ofs[0..n], ofs[n] = total
__global__ __launch_bounds__(1024) void k_scan_small(const int* cnt, int* ofs, int n){
  __shared__ int buf[1024];
  int t = threadIdx.x;
  int v = (t < n) ? cnt[t] : 0;
  buf[t] = v;
  __syncthreads();
  for (int d = 1; d < 1024; d <<= 1){
    int x = (t >= d) ? buf[t - d] : 0;
    __syncthreads();
    buf[t] += x;
    __syncthreads();
  }
  if (t < n) ofs[t] = (t == 0) ? 0 : buf[t - 1];
  if (t == 0) ofs[n] = buf[n - 1];
}

__global__ __launch_bounds__(1024) void k_scan_blocks(const int* cnt, int* ofs, int n, int* bsum){
  __shared__ int buf[1024];
  int t = threadIdx.x;
  int gi = blockIdx.x * 1024 + t;
  int v = (gi < n) ? cnt[gi] : 0;
  buf[t] = v;
  __syncthreads();
  for (int d = 1; d < 1024; d <<= 1){
    int x = (t >= d) ? buf[t - d] : 0;
    __syncthreads();
    buf[t] += x;
    __syncthreads();
  }
  if (gi < n) ofs[gi] = buf[t] - v;   // exclusive within block
  if (t == 1023) bsum[blockIdx.x] = buf[1023];
}

__global__ __launch_bounds__(1024) void k_scan_add(int* ofs, const int* boff, int n, int nblk){
  int gi = blockIdx.x * 1024 + threadIdx.x;
  if (gi < n) ofs[gi] += boff[blockIdx.x];
  if (gi == 0) ofs[n] = boff[nblk];
}

// ---------------- batchnorm over companies per timestep ----------------
__global__ __launch_bounds__(256) void k_bn(const float* ts, const float* gamma, const float* beta, float* outp){
  __shared__ float ss[256], s2[256];
  int t = blockIdx.x, tid = threadIdx.x;
  float a = 0.f, b = 0.f;
  for (int c = tid; c < NCC; c += 256){
    float v = ts[(c * TTT + t) * FFF + 3];
    a += v; b += v * v;
  }
  ss[tid] = a; s2[tid] = b;
  __syncthreads();
  for (int d = 128; d > 0; d >>= 1){
    if (tid < d){ ss[tid] += ss[tid + d]; s2[tid] += s2[tid + d]; }
    __syncthreads();
  }
  float mean = ss[0] / (float)NCC;
  float var  = s2[0] / (float)NCC - mean * mean;
  float rstd = rsqrtf(var + 1e-5f);
  float g = gamma[t], be = beta[t];
  for (int c = tid; c < NCC; c += 256){
    float v = ts[(c * TTT + t) * FFF + 3];
    outp[c * TTT + t] = (v - mean) * rstd * g + be;
  }
}

// ---------------- LSTM layer 0 (input dim 1) ----------------
__global__ __launch_bounds__(256) void k_lstm0(const float* tsn, const float* Wih0, const float* Whh0,
                                               const float* bih0, const float* bhh0, float* h0seq){
  __shared__ __align__(16) u16 sW[64 * 256];  // [k][j] bf16 of Whh0^T
  __shared__ float sWi[256];
  __shared__ float sB[256];
  int tid = threadIdx.x;
  for (int i = tid; i < 64 * 256; i += 256){
    int j = i >> 6, k = i & 63;
    sW[k * 256 + j] = f2bf(Whh0[i]);
  }
  if (tid < 256){ sWi[tid] = Wih0[tid]; sB[tid] = bih0[tid] + bhh0[tid]; }
  __syncthreads();
  int wave = tid >> 6, lane = tid & 63;
  int c = blockIdx.x * 4 + wave;
  if (c >= NCC) return;
  float wi_i = sWi[lane], wi_f = sWi[64 + lane], wi_g = sWi[128 + lane], wi_o = sWi[192 + lane];
  float b_i = sB[lane], b_f = sB[64 + lane], b_g = sB[128 + lane], b_o = sB[192 + lane];
  float h = 0.f, cs = 0.f;
  for (int t = 0; t < TTT; ++t){
    float x = tsn[c * TTT + t];
    float gi = b_i + x * wi_i, gf = b_f + x * wi_f, gg = b_g + x * wi_g, go = b_o + x * wi_o;
    #pragma unroll 4
    for (int k = 0; k < 64; ++k){
      float hk = __shfl(h, k, 64);
      const u16* w = &sW[k * 256 + lane];
      gi += hk * bf2f(w[0]);
      gf += hk * bf2f(w[64]);
      gg += hk * bf2f(w[128]);
      go += hk * bf2f(w[192]);
    }
    cs = sigm(gf) * cs + sigm(gi) * tanhf(gg);
    h  = sigm(go) * tanhf(cs);
    h0seq[(c * TTT + t) * 64 + lane] = h;
  }
}

// ---------------- LSTM layer 1 + fc + emb ----------------
__global__ __launch_bounds__(256, 1) void k_lstm1(const float* h0seq, const float* Wih1, const float* Whh1,
                                                  const float* bih1, const float* bhh1,
                                                  const float* fcW, const float* fcb,
                                                  const float* emb, const int* ids, float* comp0){
  __shared__ __align__(16) u16 sWi[64 * 256];
  __shared__ __align__(16) u16 sWh[64 * 256];
  int tid = threadIdx.x;
  for (int i = tid; i < 64 * 256; i += 256){
    int j = i >> 6, k = i & 63;
    sWi[k * 256 + j] = f2bf(Wih1[i]);
    sWh[k * 256 + j] = f2bf(Whh1[i]);
  }
  __syncthreads();
  int wave = tid >> 6, lane = tid & 63;
  int c = blockIdx.x * 4 + wave;
  int ci = (c < NCC) ? c : (NCC - 1);
  float b_i = bih1[lane]        + bhh1[lane];
  float b_f = bih1[64 + lane]   + bhh1[64 + lane];
  float b_g = bih1[128 + lane]  + bhh1[128 + lane];
  float b_o = bih1[192 + lane]  + bhh1[192 + lane];
  float h = 0.f, cs = 0.f;
  for (int t = 0; t < TTT; ++t){
    float x = h0seq[(ci * TTT + t) * 64 + lane];
    float gi = b_i, gf = b_f, gg = b_g, go = b_o;
    #pragma unroll 4
    for (int k = 0; k < 64; ++k){
      float xk = __shfl(x, k, 64);
      float hk = __shfl(h, k, 64);
      const u16* wi = &sWi[k * 256 + lane];
      const u16* wh = &sWh[k * 256 + lane];
      gi += xk * bf2f(wi[0])   + hk * bf2f(wh[0]);
      gf += xk * bf2f(wi[64])  + hk * bf2f(wh[64]);
      gg += xk * bf2f(wi[128]) + hk * bf2f(wh[128]);
      go += xk * bf2f(wi[192]) + hk * bf2f(wh[192]);
    }
    cs = sigm(gf) * cs + sigm(gi) * tanhf(gg);
    h  = sigm(go) * tanhf(cs);
  }
  // fc: reuse sWi region as f32 fcW^T [k][d]
  __syncthreads();
  float* fws = (float*)sWi;
  for (int i = tid; i < 64 * 64; i += 256){
    int d = i >> 6, k = i & 63;
    fws[k * 64 + d] = fcW[i];
  }
  __syncthreads();
  float y = fcb[lane];
  #pragma unroll 4
  for (int k = 0; k < 64; ++k){
    float hk = __shfl(h, k, 64);
    y += hk * fws[k * 64 + lane];
  }
  y = fmaxf(y, 0.f);
  if (c < NCC) comp0[c * 64 + lane] = y + emb[ids[c] * 64 + lane];
}

// ---------------- transpose proj_W [64][768] -> [768][64] ----------------
__global__ __launch_bounds__(256) void k_transW(const float* W, float* Wt){
  int i = blockIdx.x * 256 + threadIdx.x;
  if (i < 64 * 768){
    int n = i / 768, k = i % 768;
    Wt[k * 64 + n] = W[i];
  }
}

// ---------------- proj GEMM: sent0 = bf16(sentence_x @ proj_W.T + b) ----------------
__global__ __launch_bounds__(256) void k_proj(const float* __restrict__ A, const float* __restrict__ WtP,
                                              const float* __restrict__ pb, u16* __restrict__ sent0){
  __shared__ __align__(16) float At[64 * 68];  // [k][s], padded
  __shared__ __align__(16) float Wc[64 * 64];  // [k][n]
  int tid = threadIdx.x;
  int s0 = blockIdx.x * 64;
  int n0 = (tid & 15) * 4, sG = (tid >> 4) * 4;
  float acc[4][4] = {};
  for (int kc = 0; kc < 12; ++kc){
    __syncthreads();
    #pragma unroll
    for (int r = 0; r < 4; ++r){
      int q = tid + 256 * r;
      int sL = q >> 4, kb = q & 15;
      const float4 v = *(const float4*)&A[(size_t)(s0 + sL) * 768 + kc * 64 + kb * 4];
      At[(kb * 4 + 0) * 68 + sL] = v.x;
      At[(kb * 4 + 1) * 68 + sL] = v.y;
      At[(kb * 4 + 2) * 68 + sL] = v.z;
      At[(kb * 4 + 3) * 68 + sL] = v.w;
      *(float4*)&Wc[sL * 64 + kb * 4] = *(const float4*)&WtP[(size_t)(kc * 64 + sL) * 64 + kb * 4];
    }
    __syncthreads();
    #pragma unroll 4
    for (int k = 0; k < 64; ++k){
      float4 a4 = *(const float4*)&At[k * 68 + sG];
      float4 w4 = *(const float4*)&Wc[k * 64 + n0];
      float a_[4] = {a4.x, a4.y, a4.z, a4.w};
      float w_[4] = {w4.x, w4.y, w4.z, w4.w};
      #pragma unroll
      for (int i = 0; i < 4; ++i)
        #pragma unroll
        for (int j = 0; j < 4; ++j)
          acc[i][j] += a_[i] * w_[j];
    }
  }
  float4 pbv = *(const float4*)&pb[n0];
  float pb_[4] = {pbv.x, pbv.y, pbv.z, pbv.w};
  #pragma unroll
  for (int i = 0; i < 4; ++i){
    ushort4 o;
    o.x = f2bf(acc[i][0] + pb_[0]);
    o.y = f2bf(acc[i][1] + pb_[1]);
    o.z = f2bf(acc[i][2] + pb_[2]);
    o.w = f2bf(acc[i][3] + pb_[3]);
    *(ushort4*)&sent0[(size_t)(s0 + sG + i) * 64 + n0] = o;
  }
}

// ---------------- sentence GIN (in-place capable): sentOut = LReLU((sentIn + seg_sum(comp)) @ W.T + b) ----------------
__global__ __launch_bounds__(256) void k_sgin(const u16* __restrict__ sentIn, const float* __restrict__ compIn,
                                              const int* __restrict__ ofs, const int* __restrict__ bkt,
                                              const float* __restrict__ W, const float* __restrict__ b,
                                              const float* __restrict__ aP, u16* __restrict__ sentOut){
  __shared__ __align__(16) float Wt[64 * 64];
  __shared__ __align__(16) float Xt[64 * 68];
  int tid = threadIdx.x;
  for (int i = tid; i < 4096; i += 256){
    int j = i >> 6, k = i & 63;
    Wt[k * 64 + j] = W[i];
  }
  int wave = tid >> 6, lane = tid & 63;
  int sBase = blockIdx.x * 64;
  for (int q = 0; q < 16; ++q){
    int sL = wave * 16 + q;
    int s = sBase + sL;
    float acc = bf2f(sentIn[(size_t)s * 64 + lane]);
    int e0 = ofs[s], e1 = ofs[s + 1];
    for (int e = e0; e < e1; ++e){
      int src = bkt[e];
      acc += compIn[src * 64 + lane];
    }
    Xt[lane * 68 + sL] = acc;
  }
  __syncthreads();
  int n0 = (tid & 15) * 4, sG = (tid >> 4) * 4;
  float acc[4][4] = {};
  #pragma unroll 4
  for (int k = 0; k < 64; ++k){
    float4 a4 = *(const float4*)&Xt[k * 68 + sG];
    float4 w4 = *(const float4*)&Wt[k * 64 + n0];
    float a_[4] = {a4.x, a4.y, a4.z, a4.w};
    float w_[4] = {w4.x, w4.y, w4.z, w4.w};
    #pragma unroll
    for (int i = 0; i < 4; ++i)
      #pragma unroll
      for (int j = 0; j < 4; ++j)
        acc[i][j] += a_[i] * w_[j];
  }
  float alpha = *aP;
  float4 bv = *(const float4*)&b[n0];
  float b_[4] = {bv.x, bv.y, bv.z, bv.w};
  __syncthreads();  // ensure all reads of sentIn rows done before (potential) in-place overwrite
  #pragma unroll
  for (int i = 0; i < 4; ++i){
    ushort4 o;
    #pragma unroll
    for (int j = 0; j < 4; ++j){
      float h = acc[i][j] + b_[j];
      h = (h >= 0.f) ? h : alpha * h;
      ((u16*)&o)[j] = f2bf(h);
    }
    *(ushort4*)&sentOut[(size_t)(sBase + sG + i) * 64 + n0] = o;
  }
}

// ---------------- company GIN: compOut = LReLU((comp+msgA)@Wa.T+ba) + LReLU((comp+msgB)@Wb.T+bb) ----------------
__global__ __launch_bounds__(256) void k_cgin(const float* __restrict__ compIn, const u16* __restrict__ sentIn,
                                              const int* __restrict__ ofsA, const int* __restrict__ bktA,
                                              const int* __restrict__ ofsB, const int* __restrict__ bktB,
                                              const float* __restrict__ Wa, const float* __restrict__ ba, const float* aaP,
                                              const float* __restrict__ Wb, const float* __restrict__ bb, const float* abP,
                                              float* __restrict__ compOut){
  __shared__ __align__(16) float Wat[4096];
  __shared__ __align__(16) float Wbt[4096];
  __shared__ float xa[64], xb[64];
  __shared__ float part[4][2][64];
  __shared__ float outab[128];
  int tid = threadIdx.x;
  for (int i = tid; i < 4096; i += 256){
    int j = i >> 6, k = i & 63;
    Wat[k * 64 + j] = Wa[i];
    Wbt[k * 64 + j] = Wb[i];
  }
  int wave = tid >> 6, lane = tid & 63;
  int c = blockIdx.x;
  float accA = 0.f, accB = 0.f;
  int a0 = ofsA[c], a1 = ofsA[c + 1];
  for (int e = a0 + wave; e < a1; e += 4) accA += compIn[bktA[e] * 64 + lane];
  int b0 = ofsB[c], b1 = ofsB[c + 1];
  #pragma unroll 2
  for (int e = b0 + wave; e < b1; e += 4) accB += bf2f(sentIn[(size_t)bktB[e] * 64 + lane]);
  part[wave][0][lane] = accA;
  part[wave][1][lane] = accB;
  __syncthreads();
  if (tid < 64){
    float ma = part[0][0][tid] + part[1][0][tid] + part[2][0][tid] + part[3][0][tid];
    float mb = part[0][1][tid] + part[1][1][tid] + part[2][1][tid] + part[3][1][tid];
    float ci = compIn[c * 64 + tid];
    xa[tid] = ci + ma;
    xb[tid] = ci + mb;
  }
  __syncthreads();
  if (tid < 128){
    int j = tid & 63;
    const float* X  = (tid < 64) ? xa : xb;
    const float* Wt = (tid < 64) ? Wat : Wbt;
    float acc = (tid < 64) ? ba[j] : bb[j];
    #pragma unroll 4
    for (int k = 0; k < 64; ++k) acc += X[k] * Wt[k * 64 + j];
    float al = (tid < 64) ? *aaP : *abP;
    outab[tid] = (acc >= 0.f) ? acc : al * acc;
  }
  __syncthreads();
  if (tid < 64) compOut[c * 64 + tid] = outab[tid] + outab[64 + tid];
}

// ---------------- final classifier ----------------
__global__ __launch_bounds__(256) void k_cls(const float* __restrict__ comp, const float* __restrict__ W,
                                             const float* __restrict__ b, float* __restrict__ outp){
  int i = blockIdx.x * 256 + threadIdx.x;
  if (i >= NCC * 2) return;
  int c = i >> 1, j = i & 1;
  float acc = b[j];
  #pragma unroll 4
  for (int k = 0; k < 64; ++k) acc += comp[c * 64 + k] * W[j * 64 + k];
  outp[i] = acc;
}

extern "C" void kernel_launch(void* const* d_in, const int* in_sizes, int n_in,
                              void* d_out, int out_size, void* d_ws, size_t ws_size,
                              hipStream_t stream) {
  (void)in_sizes; (void)n_in; (void)out_size; (void)ws_size;
  const float* company_ts = (const float*)d_in[0];
  const float* sentence_x = (const float*)d_in[1];
  const int*   company_ids = (const int*)d_in[2];
  const int*   c2c_src = (const int*)d_in[3];
  const int*   c2c_dst = (const int*)d_in[4];
  const int*   s2c_src = (const int*)d_in[5];
  const int*   s2c_dst = (const int*)d_in[6];
  const int*   c2s_src = (const int*)d_in[7];
  const int*   c2s_dst = (const int*)d_in[8];
  const float* bn_gamma = (const float*)d_in[9];
  const float* bn_beta  = (const float*)d_in[10];
  const float* Wih0 = (const float*)d_in[11];
  const float* Whh0 = (const float*)d_in[12];
  const float* bih0 = (const float*)d_in[13];
  const float* bhh0 = (const float*)d_in[14];
  const float* Wih1 = (const float*)d_in[15];
  const float* Whh1 = (const float*)d_in[16];
  const float* bih1 = (const float*)d_in[17];
  const float* bhh1 = (const float*)d_in[18];
  const float* fc_W = (const float*)d_in[19];
  const float* fc_b = (const float*)d_in[20];
  const float* comp_emb = (const float*)d_in[21];
  const float* proj_W = (const float*)d_in[22];
  const float* proj_b = (const float*)d_in[23];
  const float* gin_W = (const float*)d_in[24];
  const float* gin_b = (const float*)d_in[25];
  const float* gin_a = (const float*)d_in[26];
  const float* cls_W = (const float*)d_in[27];
  const float* cls_b = (const float*)d_in[28];
  float* outp = (float*)d_out;

  char* ws = (char*)d_ws;
  size_t off = 0;
  auto alloc = [&](size_t bytes)->char* {
    char* r = ws + off;
    off += (bytes + 255) & ~(size_t)255;
    return r;
  };
  float* ts_norm = (float*)alloc((size_t)NCC * TTT * 4);
  float* h0seq   = (float*)alloc((size_t)NCC * TTT * 64 * 4);
  float* comp0   = (float*)alloc((size_t)NCC * 64 * 4);
  float* comp1   = (float*)alloc((size_t)NCC * 64 * 4);
  float* comp2   = (float*)alloc((size_t)NCC * 64 * 4);
  u16*   sent0   = (u16*)alloc((size_t)SSN * 64 * 2);   // reused in place as sent1
  float* WtP     = (float*)alloc((size_t)768 * 64 * 4);
  int*   cur_c2c = (int*)alloc((size_t)(NCC + NCC + SSN) * 4);  // contiguous: c2c | s2c | c2s
  int*   cur_s2c = cur_c2c + NCC;
  int*   cur_c2s = cur_s2c + NCC;
  int*   off_c2c = (int*)alloc((size_t)(NCC + 1) * 4);
  int*   off_s2c = (int*)alloc((size_t)(NCC + 1) * 4);
  int*   off_c2s = (int*)alloc((size_t)(SSN + 1) * 4);
  int*   bkt_c2c = (int*)alloc((size_t)ECN * 4);
  int*   bkt_s2c = (int*)alloc((size_t)EEN * 4);
  int*   bkt_c2s = (int*)alloc((size_t)EEN * 4);
  int*   bsum    = (int*)alloc(256 * 4);
  int*   boff    = (int*)alloc(257 * 4);

  const int ZN = NCC + NCC + SSN;

  // --- CSR builds ---
  k_zero<<<(ZN + 255) / 256, 256, 0, stream>>>(cur_c2c, ZN);
  k_hist<<<(ECN + 255) / 256, 256, 0, stream>>>(c2c_dst, ECN, cur_c2c);
  k_hist<<<(EEN + 255) / 256, 256, 0, stream>>>(s2c_dst, EEN, cur_s2c);
  k_hist<<<(EEN + 255) / 256, 256, 0, stream>>>(c2s_dst, EEN, cur_c2s);
  k_scan_small<<<1, 1024, 0, stream>>>(cur_c2c, off_c2c, NCC);
  k_scan_small<<<1, 1024, 0, stream>>>(cur_s2c, off_s2c, NCC);
  k_scan_blocks<<<CSBLK, 1024, 0, stream>>>(cur_c2s, off_c2s, SSN, bsum);
  k_scan_small<<<1, 1024, 0, stream>>>(bsum, boff, CSBLK);
  k_scan_add<<<CSBLK, 1024, 0, stream>>>(off_c2s, boff, SSN, CSBLK);
  k_copy<<<(NCC + 255) / 256, 256, 0, stream>>>(off_c2c, cur_c2c, NCC);
  k_copy<<<(NCC + 255) / 256, 256, 0, stream>>>(off_s2c, cur_s2c, NCC);
  k_copy<<<(SSN + 255) / 256, 256, 0, stream>>>(off_c2s, cur_c2s, SSN);
  k_scatter<<<(ECN + 255) / 256, 256, 0, stream>>>(c2c_src, c2c_dst, ECN, cur_c2c, bkt_c2c);
  k_scatter<<<(EEN + 255) / 256, 256, 0, stream>>>(s2c_src, s2c_dst, EEN, cur_s2c, bkt_s2c);
  k_scatter<<<(EEN + 255) / 256, 256, 0, stream>>>(c2s_src, c2s_dst, EEN, cur_c2s, bkt_c2s);

  // --- time-series branch ---
  k_bn<<<TTT, 256, 0, stream>>>(company_ts, bn_gamma, bn_beta, ts_norm);
  k_lstm0<<<(NCC + 3) / 4, 256, 0, stream>>>(ts_norm, Wih0, Whh0, bih0, bhh0, h0seq);
  k_lstm1<<<(NCC + 3) / 4, 256, 0, stream>>>(h0seq, Wih1, Whh1, bih1, bhh1, fc_W, fc_b,
                                             comp_emb, company_ids, comp0);

  // --- sentence projection ---
  k_transW<<<(64 * 768 + 255) / 256, 256, 0, stream>>>(proj_W, WtP);
  k_proj<<<SSN / 64, 256, 0, stream>>>(sentence_x, WtP, proj_b, sent0);

  // --- GIN layer 0 ---
  k_cgin<<<NCC, 256, 0, stream>>>(comp0, sent0,
                                  off_c2c, bkt_c2c, off_s2c, bkt_s2c,
                                  gin_W + 0 * 4096, gin_b + 0 * 64, gin_a + 0,
                                  gin_W + 1 * 4096, gin_b + 1 * 64, gin_a + 1,
                                  comp1);
  k_sgin<<<SSN / 64, 256, 0, stream>>>(sent0, comp0, off_c2s, bkt_c2s,
                                       gin_W + 2 * 4096, gin_b + 2 * 64, gin_a + 2,
                                       sent0 /* in place: each row reads only itself */);

  // --- GIN layer 1 (new_sent of layer 1 is dead code) ---
  k_cgin<<<NCC, 256, 0, stream>>>(comp1, sent0,
                                  off_c2c, bkt_c2c, off_s2c, bkt_s2c,
                                  gin_W + 3 * 4096, gin_b + 3 * 64, gin_a + 3,
                                  gin_W + 4 * 4096, gin_b + 4 * 64, gin_a + 4,
                                  comp2);

  // --- classifier ---
  k_cls<<<(NCC * 2 + 255) / 256, 256, 0, stream>>>(comp2, cls_W, cls_b, outp);
}

// Round 2
// 934.421 us; speedup vs baseline: 1.7039x; 1.7039x over previous
//
#include <hip/hip_runtime.h>

#define NCC 617
#define TTT 15
#define FFF 5
#define SSN 200000
#define EEN 1000000
#define ECN 20000
#define CSBLK 196   /* ceil(SSN/1024) */
#define NB2 512
#define EPB2 ((EEN + NB2 - 1) / NB2)   /* 1954 */

typedef unsigned short u16;
typedef unsigned int   u32;

__device__ __forceinline__ float bf2f(u16 u){ return __uint_as_float(((u32)u) << 16); }
__device__ __forceinline__ u16 f2bf(float f){
  u32 x = __float_as_uint(f);
  u32 r = (x + 0x7fffu + ((x >> 16) & 1u)) >> 16;
  return (u16)r;
}
__device__ __forceinline__ float sigm(float x){ return 1.0f / (1.0f + __expf(-x)); }

// ---------------- utility kernels ----------------
__global__ __launch_bounds__(256) void k_zero(int* p, int n){
  int i = blockIdx.x * 256 + threadIdx.x;
  if (i < n) p[i] = 0;
}

// combined histogram for c2c (global atomics, 20k edges) and c2s (200k counters, low contention)
__global__ __launch_bounds__(256) void k_hist_all(const int* d1, int n1, int* c1,
                                                  const int* d2, int n2, int* c2){
  int i = blockIdx.x * 256 + threadIdx.x;
  if (i < n1) atomicAdd(&c1[d1[i]], 1);
  else if (i < n1 + n2) atomicAdd(&c2[d2[i - n1]], 1);
}

__global__ __launch_bounds__(256) void k_scatter_all(const int* s1, const int* d1, const int* off1, int* cnt1, int* bkt1, int n1,
                                                     const int* s2, const int* d2, const int* off2, int* cnt2, int* bkt2, int n2){
  int i = blockIdx.x * 256 + threadIdx.x;
  if (i < n1){
    int d = d1[i]; int p = off1[d] + atomicAdd(&cnt1[d], 1); bkt1[p] = s1[i];
  } else if (i < n1 + n2){
    int k = i - n1;
    int d = d2[k]; int p = off2[d] + atomicAdd(&cnt2[d], 1); bkt2[p] = s2[k];
  }
}

// ---- s2c CSR via LDS-privatized counting sort (no contended global atomics) ----
__global__ __launch_bounds__(256) void k_hist2(const int* __restrict__ dst, int* __restrict__ blockHist){
  __shared__ int h[NCC];
  int b = blockIdx.x, tid = threadIdx.x;
  for (int i = tid; i < NCC; i += 256) h[i] = 0;
  __syncthreads();
  int e0 = b * EPB2;
  int e1 = e0 + EPB2; if (e1 > EEN) e1 = EEN;
  for (int e = e0 + tid; e < e1; e += 256) atomicAdd(&h[dst[e]], 1);
  __syncthreads();
  for (int i = tid; i < NCC; i += 256) blockHist[i * NB2 + b] = h[i];
}

// one wave per destination: exclusive prefix over the 512 per-block counts (in place) + column total
__global__ __launch_bounds__(64) void k_colscan(int* __restrict__ blockHist, int* __restrict__ colTotal){
  int d = blockIdx.x, lane = threadIdx.x;
  int base = 0;
  for (int j = 0; j < NB2; j += 64){
    int v = blockHist[d * NB2 + j + lane];
    int orig = v;
    #pragma unroll
    for (int s = 1; s < 64; s <<= 1){
      int t = __shfl_up(v, s, 64);
      if (lane >= s) v += t;
    }
    blockHist[d * NB2 + j + lane] = base + v - orig;   // exclusive within column
    base += __shfl(v, 63, 64);
  }
  if (lane == 0) colTotal[d] = base;
}

__global__ __launch_bounds__(256) void k_scatter2(const int* __restrict__ src, const int* __restrict__ dst,
                                                  const int* __restrict__ blockHist, const int* __restrict__ off,
                                                  int* __restrict__ bkt){
  __shared__ int cur[NCC];
  int b = blockIdx.x, tid = threadIdx.x;
  for (int i = tid; i < NCC; i += 256) cur[i] = off[i] + blockHist[i * NB2 + b];
  __syncthreads();
  int e0 = b * EPB2;
  int e1 = e0 + EPB2; if (e1 > EEN) e1 = EEN;
  for (int e = e0 + tid; e < e1; e += 256){
    int d = dst[e];
    int p = atomicAdd(&cur[d], 1);
    bkt[p] = src[e];
  }
}

// exclusive scan for n <= 1024, writes ofs[0..n], ofs[n] = total
__global__ __launch_bounds__(1024) void k_scan_small(const int* cnt, int* ofs, int n){
  __shared__ int buf[1024];
  int t = threadIdx.x;
  int v = (t < n) ? cnt[t] : 0;
  buf[t] = v;
  __syncthreads();
  for (int d = 1; d < 1024; d <<= 1){
    int x = (t >= d) ? buf[t - d] : 0;
    __syncthreads();
    buf[t] += x;
    __syncthreads();
  }
  if (t < n) ofs[t] = (t == 0) ? 0 : buf[t - 1];
  if (t == 0) ofs[n] = buf[n - 1];
}

__global__ __launch_bounds__(1024) void k_scan_blocks(const int* cnt, int* ofs, int n, int* bsum){
  __shared__ int buf[1024];
  int t = threadIdx.x;
  int gi = blockIdx.x * 1024 + t;
  int v = (gi < n) ? cnt[gi] : 0;
  buf[t] = v;
  __syncthreads();
  for (int d = 1; d < 1024; d <<= 1){
    int x = (t >= d) ? buf[t - d] : 0;
    __syncthreads();
    buf[t] += x;
    __syncthreads();
  }
  if (gi < n) ofs[gi] = buf[t] - v;   // exclusive within block
  if (t == 1023) bsum[blockIdx.x] = buf[1023];
}

__global__ __launch_bounds__(1024) void k_scan_add(int* ofs, const int* boff, int n, int nblk){
  int gi = blockIdx.x * 1024 + threadIdx.x;
  if (gi < n) ofs[gi] += boff[blockIdx.x];
  if (gi == 0) ofs[n] = boff[nblk];
}

// ---------------- batchnorm over companies per timestep ----------------
__global__ __launch_bounds__(256) void k_bn(const float* ts, const float* gamma, const float* beta, float* outp){
  __shared__ float ss[256], s2[256];
  int t = blockIdx.x, tid = threadIdx.x;
  float a = 0.f, b = 0.f;
  for (int c = tid; c < NCC; c += 256){
    float v = ts[(c * TTT + t) * FFF + 3];
    a += v; b += v * v;
  }
  ss[tid] = a; s2[tid] = b;
  __syncthreads();
  for (int d = 128; d > 0; d >>= 1){
    if (tid < d){ ss[tid] += ss[tid + d]; s2[tid] += s2[tid + d]; }
    __syncthreads();
  }
  float mean = ss[0] / (float)NCC;
  float var  = s2[0] / (float)NCC - mean * mean;
  float rstd = rsqrtf(var + 1e-5f);
  float g = gamma[t], be = beta[t];
  for (int c = tid; c < NCC; c += 256){
    float v = ts[(c * TTT + t) * FFF + 3];
    outp[c * TTT + t] = (v - mean) * rstd * g + be;
  }
}

// ---------------- LSTM layer 0 (input dim 1) ----------------
__global__ __launch_bounds__(256) void k_lstm0(const float* tsn, const float* Wih0, const float* Whh0,
                                               const float* bih0, const float* bhh0, float* h0seq){
  __shared__ __align__(16) u16 sW[64 * 256];  // [k][j] bf16 of Whh0^T
  __shared__ float sWi[256];
  __shared__ float sB[256];
  int tid = threadIdx.x;
  for (int i = tid; i < 64 * 256; i += 256){
    int j = i >> 6, k = i & 63;
    sW[k * 256 + j] = f2bf(Whh0[i]);
  }
  if (tid < 256){ sWi[tid] = Wih0[tid]; sB[tid] = bih0[tid] + bhh0[tid]; }
  __syncthreads();
  int wave = tid >> 6, lane = tid & 63;
  int c = blockIdx.x * 4 + wave;
  if (c >= NCC) return;
  float wi_i = sWi[lane], wi_f = sWi[64 + lane], wi_g = sWi[128 + lane], wi_o = sWi[192 + lane];
  float b_i = sB[lane], b_f = sB[64 + lane], b_g = sB[128 + lane], b_o = sB[192 + lane];
  float h = 0.f, cs = 0.f;
  for (int t = 0; t < TTT; ++t){
    float x = tsn[c * TTT + t];
    float gi = b_i + x * wi_i, gf = b_f + x * wi_f, gg = b_g + x * wi_g, go = b_o + x * wi_o;
    #pragma unroll 4
    for (int k = 0; k < 64; ++k){
      float hk = __shfl(h, k, 64);
      const u16* w = &sW[k * 256 + lane];
      gi += hk * bf2f(w[0]);
      gf += hk * bf2f(w[64]);
      gg += hk * bf2f(w[128]);
      go += hk * bf2f(w[192]);
    }
    cs = sigm(gf) * cs + sigm(gi) * tanhf(gg);
    h  = sigm(go) * tanhf(cs);
    h0seq[(c * TTT + t) * 64 + lane] = h;
  }
}

// ---------------- LSTM layer 1 + fc + emb ----------------
__global__ __launch_bounds__(256, 1) void k_lstm1(const float* h0seq, const float* Wih1, const float* Whh1,
                                                  const float* bih1, const float* bhh1,
                                                  const float* fcW, const float* fcb,
                                                  const float* emb, const int* ids, float* comp0){
  __shared__ __align__(16) u16 sWi[64 * 256];
  __shared__ __align__(16) u16 sWh[64 * 256];
  int tid = threadIdx.x;
  for (int i = tid; i < 64 * 256; i += 256){
    int j = i >> 6, k = i & 63;
    sWi[k * 256 + j] = f2bf(Wih1[i]);
    sWh[k * 256 + j] = f2bf(Whh1[i]);
  }
  __syncthreads();
  int wave = tid >> 6, lane = tid & 63;
  int c = blockIdx.x * 4 + wave;
  int ci = (c < NCC) ? c : (NCC - 1);
  float b_i = bih1[lane]        + bhh1[lane];
  float b_f = bih1[64 + lane]   + bhh1[64 + lane];
  float b_g = bih1[128 + lane]  + bhh1[128 + lane];
  float b_o = bih1[192 + lane]  + bhh1[192 + lane];
  float h = 0.f, cs = 0.f;
  for (int t = 0; t < TTT; ++t){
    float x = h0seq[(ci * TTT + t) * 64 + lane];
    float gi = b_i, gf = b_f, gg = b_g, go = b_o;
    #pragma unroll 4
    for (int k = 0; k < 64; ++k){
      float xk = __shfl(x, k, 64);
      float hk = __shfl(h, k, 64);
      const u16* wi = &sWi[k * 256 + lane];
      const u16* wh = &sWh[k * 256 + lane];
      gi += xk * bf2f(wi[0])   + hk * bf2f(wh[0]);
      gf += xk * bf2f(wi[64])  + hk * bf2f(wh[64]);
      gg += xk * bf2f(wi[128]) + hk * bf2f(wh[128]);
      go += xk * bf2f(wi[192]) + hk * bf2f(wh[192]);
    }
    cs = sigm(gf) * cs + sigm(gi) * tanhf(gg);
    h  = sigm(go) * tanhf(cs);
  }
  // fc: reuse sWi region as f32 fcW^T [k][d]
  __syncthreads();
  float* fws = (float*)sWi;
  for (int i = tid; i < 64 * 64; i += 256){
    int d = i >> 6, k = i & 63;
    fws[k * 64 + d] = fcW[i];
  }
  __syncthreads();
  float y = fcb[lane];
  #pragma unroll 4
  for (int k = 0; k < 64; ++k){
    float hk = __shfl(h, k, 64);
    y += hk * fws[k * 64 + lane];
  }
  y = fmaxf(y, 0.f);
  if (c < NCC) comp0[c * 64 + lane] = y + emb[ids[c] * 64 + lane];
}

// ---------------- transpose proj_W [64][768] -> [768][64] ----------------
__global__ __launch_bounds__(256) void k_transW(const float* W, float* Wt){
  int i = blockIdx.x * 256 + threadIdx.x;
  if (i < 64 * 768){
    int n = i / 768, k = i % 768;
    Wt[k * 64 + n] = W[i];
  }
}

// ---------------- proj GEMM: sent0 = bf16(sentence_x @ proj_W.T + b) ----------------
__global__ __launch_bounds__(256) void k_proj(const float* __restrict__ A, const float* __restrict__ WtP,
                                              const float* __restrict__ pb, u16* __restrict__ sent0){
  __shared__ __align__(16) float At[64 * 68];  // [k][s], padded
  __shared__ __align__(16) float Wc[64 * 64];  // [k][n]
  int tid = threadIdx.x;
  int s0 = blockIdx.x * 64;
  int n0 = (tid & 15) * 4, sG = (tid >> 4) * 4;
  float acc[4][4] = {};
  for (int kc = 0; kc < 12; ++kc){
    __syncthreads();
    #pragma unroll
    for (int r = 0; r < 4; ++r){
      int q = tid + 256 * r;
      int sL = q >> 4, kb = q & 15;
      const float4 v = *(const float4*)&A[(size_t)(s0 + sL) * 768 + kc * 64 + kb * 4];
      At[(kb * 4 + 0) * 68 + sL] = v.x;
      At[(kb * 4 + 1) * 68 + sL] = v.y;
      At[(kb * 4 + 2) * 68 + sL] = v.z;
      At[(kb * 4 + 3) * 68 + sL] = v.w;
      *(float4*)&Wc[sL * 64 + kb * 4] = *(const float4*)&WtP[(size_t)(kc * 64 + sL) * 64 + kb * 4];
    }
    __syncthreads();
    #pragma unroll 4
    for (int k = 0; k < 64; ++k){
      float4 a4 = *(const float4*)&At[k * 68 + sG];
      float4 w4 = *(const float4*)&Wc[k * 64 + n0];
      float a_[4] = {a4.x, a4.y, a4.z, a4.w};
      float w_[4] = {w4.x, w4.y, w4.z, w4.w};
      #pragma unroll
      for (int i = 0; i < 4; ++i)
        #pragma unroll
        for (int j = 0; j < 4; ++j)
          acc[i][j] += a_[i] * w_[j];
    }
  }
  float4 pbv = *(const float4*)&pb[n0];
  float pb_[4] = {pbv.x, pbv.y, pbv.z, pbv.w};
  #pragma unroll
  for (int i = 0; i < 4; ++i){
    ushort4 o;
    o.x = f2bf(acc[i][0] + pb_[0]);
    o.y = f2bf(acc[i][1] + pb_[1]);
    o.z = f2bf(acc[i][2] + pb_[2]);
    o.w = f2bf(acc[i][3] + pb_[3]);
    *(ushort4*)&sent0[(size_t)(s0 + sG + i) * 64 + n0] = o;
  }
}

// ---------------- sentence GIN (in-place): sentOut = LReLU((sentIn + seg_sum(comp)) @ W.T + b) ----------------
__global__ __launch_bounds__(256) void k_sgin(const u16* __restrict__ sentIn, const float* __restrict__ compIn,
                                              const int* __restrict__ ofs, const int* __restrict__ bkt,
                                              const float* __restrict__ W, const float* __restrict__ b,
                                              const float* __restrict__ aP, u16* __restrict__ sentOut){
  __shared__ __align__(16) float Wt[64 * 68];
  __shared__ __align__(16) float Xt[64 * 68];
  int tid = threadIdx.x;
  for (int i = tid; i < 4096; i += 256){
    int j = i >> 6, k = i & 63;
    Wt[k * 68 + j] = W[i];
  }
  int wave = tid >> 6, lane = tid & 63;
  int sBase = blockIdx.x * 64;
  for (int q = 0; q < 16; ++q){
    int sL = wave * 16 + q;
    int s = sBase + sL;
    float acc = bf2f(sentIn[(size_t)s * 64 + lane]);
    int e0 = ofs[s], e1 = ofs[s + 1];
    for (int e = e0; e < e1; ++e){
      int src = bkt[e];
      acc += compIn[src * 64 + lane];
    }
    Xt[lane * 68 + sL] = acc;
  }
  __syncthreads();
  int n0 = (tid & 15) * 4, sG = (tid >> 4) * 4;
  float acc[4][4] = {};
  #pragma unroll 4
  for (int k = 0; k < 64; ++k){
    float4 a4 = *(const float4*)&Xt[k * 68 + sG];
    float4 w4 = *(const float4*)&Wt[k * 68 + n0];
    float a_[4] = {a4.x, a4.y, a4.z, a4.w};
    float w_[4] = {w4.x, w4.y, w4.z, w4.w};
    #pragma unroll
    for (int i = 0; i < 4; ++i)
      #pragma unroll
      for (int j = 0; j < 4; ++j)
        acc[i][j] += a_[i] * w_[j];
  }
  float alpha = *aP;
  float4 bv = *(const float4*)&b[n0];
  float b_[4] = {bv.x, bv.y, bv.z, bv.w};
  __syncthreads();  // all reads of sentIn rows done before in-place overwrite
  #pragma unroll
  for (int i = 0; i < 4; ++i){
    ushort4 o;
    #pragma unroll
    for (int j = 0; j < 4; ++j){
      float h = acc[i][j] + b_[j];
      h = (h >= 0.f) ? h : alpha * h;
      ((u16*)&o)[j] = f2bf(h);
    }
    *(ushort4*)&sentOut[(size_t)(sBase + sG + i) * 64 + n0] = o;
  }
}

// ---------------- company GIN (1024 threads = 16 waves for gather latency hiding) ----------------
__global__ __launch_bounds__(1024) void k_cgin(const float* __restrict__ compIn, const u16* __restrict__ sentIn,
                                               const int* __restrict__ ofsA, const int* __restrict__ bktA,
                                               const int* __restrict__ ofsB, const int* __restrict__ bktB,
                                               const float* __restrict__ Wa, const float* __restrict__ ba, const float* aaP,
                                               const float* __restrict__ Wb, const float* __restrict__ bb, const float* abP,
                                               float* __restrict__ compOut){
  __shared__ __align__(16) float Wat[64 * 68];
  __shared__ __align__(16) float Wbt[64 * 68];
  __shared__ float part[16][2][64];
  __shared__ float xa[64], xb[64], outab[128];
  int tid = threadIdx.x;
  for (int i = tid; i < 4096; i += 1024){
    int j = i >> 6, k = i & 63;
    Wat[k * 68 + j] = Wa[i];
    Wbt[k * 68 + j] = Wb[i];
  }
  int wave = tid >> 6, lane = tid & 63;
  int c = blockIdx.x;
  float accA = 0.f, accB = 0.f;
  int a0 = ofsA[c], a1 = ofsA[c + 1];
  for (int e = a0 + wave; e < a1; e += 16) accA += compIn[bktA[e] * 64 + lane];
  int b0 = ofsB[c], b1 = ofsB[c + 1];
  #pragma unroll 2
  for (int e = b0 + wave; e < b1; e += 16) accB += bf2f(sentIn[(size_t)bktB[e] * 64 + lane]);
  part[wave][0][lane] = accA;
  part[wave][1][lane] = accB;
  __syncthreads();
  if (tid < 128){
    int l = tid & 63, which = tid >> 6;
    float m = 0.f;
    #pragma unroll
    for (int w = 0; w < 16; ++w) m += part[w][which][l];
    float ci = compIn[c * 64 + l];
    if (which == 0) xa[l] = ci + m; else xb[l] = ci + m;
  }
  __syncthreads();
  if (tid < 128){
    int j = tid & 63;
    const float* X  = (tid < 64) ? xa : xb;
    const float* Wt = (tid < 64) ? Wat : Wbt;
    float acc = (tid < 64) ? ba[j] : bb[j];
    #pragma unroll 4
    for (int k = 0; k < 64; ++k) acc += X[k] * Wt[k * 68 + j];
    float al = (tid < 64) ? *aaP : *abP;
    outab[tid] = (acc >= 0.f) ? acc : al * acc;
  }
  __syncthreads();
  if (tid < 64) compOut[c * 64 + tid] = outab[tid] + outab[64 + tid];
}

// ---------------- final classifier ----------------
__global__ __launch_bounds__(256) void k_cls(const float* __restrict__ comp, const float* __restrict__ W,
                                             const float* __restrict__ b, float* __restrict__ outp){
  int i = blockIdx.x * 256 + threadIdx.x;
  if (i >= NCC * 2) return;
  int c = i >> 1, j = i & 1;
  float acc = b[j];
  #pragma unroll 4
  for (int k = 0; k < 64; ++k) acc += comp[c * 64 + k] * W[j * 64 + k];
  outp[i] = acc;
}

extern "C" void kernel_launch(void* const* d_in, const int* in_sizes, int n_in,
                              void* d_out, int out_size, void* d_ws, size_t ws_size,
                              hipStream_t stream) {
  (void)in_sizes; (void)n_in; (void)out_size; (void)ws_size;
  const float* company_ts = (const float*)d_in[0];
  const float* sentence_x = (const float*)d_in[1];
  const int*   company_ids = (const int*)d_in[2];
  const int*   c2c_src = (const int*)d_in[3];
  const int*   c2c_dst = (const int*)d_in[4];
  const int*   s2c_src = (const int*)d_in[5];
  const int*   s2c_dst = (const int*)d_in[6];
  const int*   c2s_src = (const int*)d_in[7];
  const int*   c2s_dst = (const int*)d_in[8];
  const float* bn_gamma = (const float*)d_in[9];
  const float* bn_beta  = (const float*)d_in[10];
  const float* Wih0 = (const float*)d_in[11];
  const float* Whh0 = (const float*)d_in[12];
  const float* bih0 = (const float*)d_in[13];
  const float* bhh0 = (const float*)d_in[14];
  const float* Wih1 = (const float*)d_in[15];
  const float* Whh1 = (const float*)d_in[16];
  const float* bih1 = (const float*)d_in[17];
  const float* bhh1 = (const float*)d_in[18];
  const float* fc_W = (const float*)d_in[19];
  const float* fc_b = (const float*)d_in[20];
  const float* comp_emb = (const float*)d_in[21];
  const float* proj_W = (const float*)d_in[22];
  const float* proj_b = (const float*)d_in[23];
  const float* gin_W = (const float*)d_in[24];
  const float* gin_b = (const float*)d_in[25];
  const float* gin_a = (const float*)d_in[26];
  const float* cls_W = (const float*)d_in[27];
  const float* cls_b = (const float*)d_in[28];
  float* outp = (float*)d_out;

  char* ws = (char*)d_ws;
  size_t off = 0;
  auto alloc = [&](size_t bytes)->char* {
    char* r = ws + off;
    off += (bytes + 255) & ~(size_t)255;
    return r;
  };
  float* ts_norm = (float*)alloc((size_t)NCC * TTT * 4);
  float* h0seq   = (float*)alloc((size_t)NCC * TTT * 64 * 4);
  float* comp0   = (float*)alloc((size_t)NCC * 64 * 4);
  float* comp1   = (float*)alloc((size_t)NCC * 64 * 4);
  float* comp2   = (float*)alloc((size_t)NCC * 64 * 4);
  u16*   sent0   = (u16*)alloc((size_t)SSN * 64 * 2);   // reused in place as sent1
  float* WtP     = (float*)alloc((size_t)768 * 64 * 4);
  int*   blockHist = (int*)alloc((size_t)NCC * NB2 * 4);   // [d][b]
  int*   colTotal  = (int*)alloc((size_t)NCC * 4);
  // zeroed counters, contiguous: cnt_c2c | cnt2_c2c | cnt_c2s | cnt2_c2s
  int*   cnt_c2c  = (int*)alloc((size_t)(NCC + NCC + SSN + SSN) * 4);
  int*   cnt2_c2c = cnt_c2c + NCC;
  int*   cnt_c2s  = cnt2_c2c + NCC;
  int*   cnt2_c2s = cnt_c2s + SSN;
  int*   off_c2c = (int*)alloc((size_t)(NCC + 1) * 4);
  int*   off_s2c = (int*)alloc((size_t)(NCC + 1) * 4);
  int*   off_c2s = (int*)alloc((size_t)(SSN + 1) * 4);
  int*   bkt_c2c = (int*)alloc((size_t)ECN * 4);
  int*   bkt_s2c = (int*)alloc((size_t)EEN * 4);
  int*   bkt_c2s = (int*)alloc((size_t)EEN * 4);
  int*   bsum    = (int*)alloc(256 * 4);
  int*   boff    = (int*)alloc(257 * 4);

  const int ZN = NCC + NCC + SSN + SSN;

  // --- CSR builds ---
  k_zero<<<(ZN + 255) / 256, 256, 0, stream>>>(cnt_c2c, ZN);
  k_hist2<<<NB2, 256, 0, stream>>>(s2c_dst, blockHist);
  k_hist_all<<<(ECN + EEN + 255) / 256, 256, 0, stream>>>(c2c_dst, ECN, cnt_c2c, c2s_dst, EEN, cnt_c2s);
  k_colscan<<<NCC, 64, 0, stream>>>(blockHist, colTotal);
  k_scan_small<<<1, 1024, 0, stream>>>(colTotal, off_s2c, NCC);
  k_scan_small<<<1, 1024, 0, stream>>>(cnt_c2c, off_c2c, NCC);
  k_scan_blocks<<<CSBLK, 1024, 0, stream>>>(cnt_c2s, off_c2s, SSN, bsum);
  k_scan_small<<<1, 1024, 0, stream>>>(bsum, boff, CSBLK);
  k_scan_add<<<CSBLK, 1024, 0, stream>>>(off_c2s, boff, SSN, CSBLK);
  k_scatter2<<<NB2, 256, 0, stream>>>(s2c_src, s2c_dst, blockHist, off_s2c, bkt_s2c);
  k_scatter_all<<<(ECN + EEN + 255) / 256, 256, 0, stream>>>(
      c2c_src, c2c_dst, off_c2c, cnt2_c2c, bkt_c2c, ECN,
      c2s_src, c2s_dst, off_c2s, cnt2_c2s, bkt_c2s, EEN);

  // --- time-series branch ---
  k_bn<<<TTT, 256, 0, stream>>>(company_ts, bn_gamma, bn_beta, ts_norm);
  k_lstm0<<<(NCC + 3) / 4, 256, 0, stream>>>(ts_norm, Wih0, Whh0, bih0, bhh0, h0seq);
  k_lstm1<<<(NCC + 3) / 4, 256, 0, stream>>>(h0seq, Wih1, Whh1, bih1, bhh1, fc_W, fc_b,
                                             comp_emb, company_ids, comp0);

  // --- sentence projection ---
  k_transW<<<(64 * 768 + 255) / 256, 256, 0, stream>>>(proj_W, WtP);
  k_proj<<<SSN / 64, 256, 0, stream>>>(sentence_x, WtP, proj_b, sent0);

  // --- GIN layer 0 ---
  k_cgin<<<NCC, 1024, 0, stream>>>(comp0, sent0,
                                   off_c2c, bkt_c2c, off_s2c, bkt_s2c,
                                   gin_W + 0 * 4096, gin_b + 0 * 64, gin_a + 0,
                                   gin_W + 1 * 4096, gin_b + 1 * 64, gin_a + 1,
                                   comp1);
  k_sgin<<<SSN / 64, 256, 0, stream>>>(sent0, comp0, off_c2s, bkt_c2s,
                                       gin_W + 2 * 4096, gin_b + 2 * 64, gin_a + 2,
                                       sent0 /* in place */);

  // --- GIN layer 1 (new_sent of layer 1 is dead code) ---
  k_cgin<<<NCC, 1024, 0, stream>>>(comp1, sent0,
                                   off_c2c, bkt_c2c, off_s2c, bkt_s2c,
                                   gin_W + 3 * 4096, gin_b + 3 * 64, gin_a + 3,
                                   gin_W + 4 * 4096, gin_b + 4 * 64, gin_a + 4,
                                   comp2);

  // --- classifier ---
  k_cls<<<(NCC * 2 + 255) / 256, 256, 0, stream>>>(comp2, cls_W, cls_b, outp);
}

// Round 3
// 799.785 us; speedup vs baseline: 1.9908x; 1.1683x over previous
//
#include <hip/hip_runtime.h>

#define NCC 617
#define TTT 15
#define FFF 5
#define SSN 200000
#define EEN 1000000
#define ECN 20000
#define CSBLK 196   /* ceil(SSN/1024) */
#define NB2 512
#define EPB2 ((EEN + NB2 - 1) / NB2)   /* 1954 */

typedef unsigned short u16;
typedef unsigned int   u32;

using short8  = __attribute__((ext_vector_type(8))) short;
using f32x4v  = __attribute__((ext_vector_type(4))) float;

__device__ __forceinline__ float bf2f(u16 u){ return __uint_as_float(((u32)u) << 16); }
__device__ __forceinline__ u16 f2bf(float f){
  u32 x = __float_as_uint(f);
  u32 r = (x + 0x7fffu + ((x >> 16) & 1u)) >> 16;
  return (u16)r;
}
__device__ __forceinline__ u32 pk2(float a, float b){ return (u32)f2bf(a) | ((u32)f2bf(b) << 16); }
__device__ __forceinline__ float sigm(float x){ return 1.0f / (1.0f + __expf(-x)); }

// ---------------- utility kernels ----------------
__global__ __launch_bounds__(256) void k_zero(int* p, int n){
  int i = blockIdx.x * 256 + threadIdx.x;
  if (i < n) p[i] = 0;
}

// combined histogram for c2c (20k edges) and c2s (200k counters, low contention)
__global__ __launch_bounds__(256) void k_hist_all(const int* d1, int n1, int* c1,
                                                  const int* d2, int n2, int* c2){
  int i = blockIdx.x * 256 + threadIdx.x;
  if (i < n1) atomicAdd(&c1[d1[i]], 1);
  else if (i < n1 + n2) atomicAdd(&c2[d2[i - n1]], 1);
}

__global__ __launch_bounds__(256) void k_scatter_all(const int* s1, const int* d1, const int* off1, int* cnt1, int* bkt1, int n1,
                                                     const int* s2, const int* d2, const int* off2, int* cnt2, int* bkt2, int n2){
  int i = blockIdx.x * 256 + threadIdx.x;
  if (i < n1){
    int d = d1[i]; int p = off1[d] + atomicAdd(&cnt1[d], 1); bkt1[p] = s1[i];
  } else if (i < n1 + n2){
    int k = i - n1;
    int d = d2[k]; int p = off2[d] + atomicAdd(&cnt2[d], 1); bkt2[p] = s2[k];
  }
}

// ---- s2c CSR via LDS-privatized counting sort (no contended global atomics) ----
__global__ __launch_bounds__(256) void k_hist2(const int* __restrict__ dst, int* __restrict__ blockHist){
  __shared__ int h[NCC];
  int b = blockIdx.x, tid = threadIdx.x;
  for (int i = tid; i < NCC; i += 256) h[i] = 0;
  __syncthreads();
  int e0 = b * EPB2;
  int e1 = e0 + EPB2; if (e1 > EEN) e1 = EEN;
  for (int e = e0 + tid; e < e1; e += 256) atomicAdd(&h[dst[e]], 1);
  __syncthreads();
  for (int i = tid; i < NCC; i += 256) blockHist[i * NB2 + b] = h[i];
}

__global__ __launch_bounds__(64) void k_colscan(int* __restrict__ blockHist, int* __restrict__ colTotal){
  int d = blockIdx.x, lane = threadIdx.x;
  int base = 0;
  for (int j = 0; j < NB2; j += 64){
    int v = blockHist[d * NB2 + j + lane];
    int orig = v;
    #pragma unroll
    for (int s = 1; s < 64; s <<= 1){
      int t = __shfl_up(v, s, 64);
      if (lane >= s) v += t;
    }
    blockHist[d * NB2 + j + lane] = base + v - orig;   // exclusive within column
    base += __shfl(v, 63, 64);
  }
  if (lane == 0) colTotal[d] = base;
}

__global__ __launch_bounds__(256) void k_scatter2(const int* __restrict__ src, const int* __restrict__ dst,
                                                  const int* __restrict__ blockHist, const int* __restrict__ off,
                                                  int* __restrict__ bkt){
  __shared__ int cur[NCC];
  int b = blockIdx.x, tid = threadIdx.x;
  for (int i = tid; i < NCC; i += 256) cur[i] = off[i] + blockHist[i * NB2 + b];
  __syncthreads();
  int e0 = b * EPB2;
  int e1 = e0 + EPB2; if (e1 > EEN) e1 = EEN;
  for (int e = e0 + tid; e < e1; e += 256){
    int d = dst[e];
    int p = atomicAdd(&cur[d], 1);
    bkt[p] = src[e];
  }
}

// exclusive scan for n <= 1024, writes ofs[0..n], ofs[n] = total
__global__ __launch_bounds__(1024) void k_scan_small(const int* cnt, int* ofs, int n){
  __shared__ int buf[1024];
  int t = threadIdx.x;
  int v = (t < n) ? cnt[t] : 0;
  buf[t] = v;
  __syncthreads();
  for (int d = 1; d < 1024; d <<= 1){
    int x = (t >= d) ? buf[t - d] : 0;
    __syncthreads();
    buf[t] += x;
    __syncthreads();
  }
  if (t < n) ofs[t] = (t == 0) ? 0 : buf[t - 1];
  if (t == 0) ofs[n] = buf[n - 1];
}

__global__ __launch_bounds__(1024) void k_scan_blocks(const int* cnt, int* ofs, int n, int* bsum){
  __shared__ int buf[1024];
  int t = threadIdx.x;
  int gi = blockIdx.x * 1024 + t;
  int v = (gi < n) ? cnt[gi] : 0;
  buf[t] = v;
  __syncthreads();
  for (int d = 1; d < 1024; d <<= 1){
    int x = (t >= d) ? buf[t - d] : 0;
    __syncthreads();
    buf[t] += x;
    __syncthreads();
  }
  if (gi < n) ofs[gi] = buf[t] - v;   // exclusive within block
  if (t == 1023) bsum[blockIdx.x] = buf[1023];
}

__global__ __launch_bounds__(1024) void k_scan_add(int* ofs, const int* boff, int n, int nblk){
  int gi = blockIdx.x * 1024 + threadIdx.x;
  if (gi < n) ofs[gi] += boff[blockIdx.x];
  if (gi == 0) ofs[n] = boff[nblk];
}

// ---------------- batchnorm over companies per timestep ----------------
__global__ __launch_bounds__(256) void k_bn(const float* ts, const float* gamma, const float* beta, float* outp){
  __shared__ float ss[256], s2[256];
  int t = blockIdx.x, tid = threadIdx.x;
  float a = 0.f, b = 0.f;
  for (int c = tid; c < NCC; c += 256){
    float v = ts[(c * TTT + t) * FFF + 3];
    a += v; b += v * v;
  }
  ss[tid] = a; s2[tid] = b;
  __syncthreads();
  for (int d = 128; d > 0; d >>= 1){
    if (tid < d){ ss[tid] += ss[tid + d]; s2[tid] += s2[tid + d]; }
    __syncthreads();
  }
  float mean = ss[0] / (float)NCC;
  float var  = s2[0] / (float)NCC - mean * mean;
  float rstd = rsqrtf(var + 1e-5f);
  float g = gamma[t], be = beta[t];
  for (int c = tid; c < NCC; c += 256){
    float v = ts[(c * TTT + t) * FFF + 3];
    outp[c * TTT + t] = (v - mean) * rstd * g + be;
  }
}

// ---------------- LSTM layer 0 (input dim 1) ----------------
__global__ __launch_bounds__(256) void k_lstm0(const float* tsn, const float* Wih0, const float* Whh0,
                                               const float* bih0, const float* bhh0, float* h0seq){
  __shared__ __align__(16) u16 sW[64 * 256];  // [k][j] bf16 of Whh0^T
  __shared__ float sWi[256];
  __shared__ float sB[256];
  int tid = threadIdx.x;
  for (int i = tid; i < 64 * 256; i += 256){
    int j = i >> 6, k = i & 63;
    sW[k * 256 + j] = f2bf(Whh0[i]);
  }
  if (tid < 256){ sWi[tid] = Wih0[tid]; sB[tid] = bih0[tid] + bhh0[tid]; }
  __syncthreads();
  int wave = tid >> 6, lane = tid & 63;
  int c = blockIdx.x * 4 + wave;
  if (c >= NCC) return;
  float wi_i = sWi[lane], wi_f = sWi[64 + lane], wi_g = sWi[128 + lane], wi_o = sWi[192 + lane];
  float b_i = sB[lane], b_f = sB[64 + lane], b_g = sB[128 + lane], b_o = sB[192 + lane];
  float h = 0.f, cs = 0.f;
  for (int t = 0; t < TTT; ++t){
    float x = tsn[c * TTT + t];
    float gi = b_i + x * wi_i, gf = b_f + x * wi_f, gg = b_g + x * wi_g, go = b_o + x * wi_o;
    #pragma unroll 4
    for (int k = 0; k < 64; ++k){
      float hk = __shfl(h, k, 64);
      const u16* w = &sW[k * 256 + lane];
      gi += hk * bf2f(w[0]);
      gf += hk * bf2f(w[64]);
      gg += hk * bf2f(w[128]);
      go += hk * bf2f(w[192]);
    }
    cs = sigm(gf) * cs + sigm(gi) * tanhf(gg);
    h  = sigm(go) * tanhf(cs);
    h0seq[(c * TTT + t) * 64 + lane] = h;
  }
}

// ---------------- LSTM layer 1 + fc + emb ----------------
__global__ __launch_bounds__(256, 1) void k_lstm1(const float* h0seq, const float* Wih1, const float* Whh1,
                                                  const float* bih1, const float* bhh1,
                                                  const float* fcW, const float* fcb,
                                                  const float* emb, const int* ids, float* comp0){
  __shared__ __align__(16) u16 sWi[64 * 256];
  __shared__ __align__(16) u16 sWh[64 * 256];
  int tid = threadIdx.x;
  for (int i = tid; i < 64 * 256; i += 256){
    int j = i >> 6, k = i & 63;
    sWi[k * 256 + j] = f2bf(Wih1[i]);
    sWh[k * 256 + j] = f2bf(Whh1[i]);
  }
  __syncthreads();
  int wave = tid >> 6, lane = tid & 63;
  int c = blockIdx.x * 4 + wave;
  int ci = (c < NCC) ? c : (NCC - 1);
  float b_i = bih1[lane]        + bhh1[lane];
  float b_f = bih1[64 + lane]   + bhh1[64 + lane];
  float b_g = bih1[128 + lane]  + bhh1[128 + lane];
  float b_o = bih1[192 + lane]  + bhh1[192 + lane];
  float h = 0.f, cs = 0.f;
  for (int t = 0; t < TTT; ++t){
    float x = h0seq[(ci * TTT + t) * 64 + lane];
    float gi = b_i, gf = b_f, gg = b_g, go = b_o;
    #pragma unroll 4
    for (int k = 0; k < 64; ++k){
      float xk = __shfl(x, k, 64);
      float hk = __shfl(h, k, 64);
      const u16* wi = &sWi[k * 256 + lane];
      const u16* wh = &sWh[k * 256 + lane];
      gi += xk * bf2f(wi[0])   + hk * bf2f(wh[0]);
      gf += xk * bf2f(wi[64])  + hk * bf2f(wh[64]);
      gg += xk * bf2f(wi[128]) + hk * bf2f(wh[128]);
      go += xk * bf2f(wi[192]) + hk * bf2f(wh[192]);
    }
    cs = sigm(gf) * cs + sigm(gi) * tanhf(gg);
    h  = sigm(go) * tanhf(cs);
  }
  __syncthreads();
  float* fws = (float*)sWi;
  for (int i = tid; i < 64 * 64; i += 256){
    int d = i >> 6, k = i & 63;
    fws[k * 64 + d] = fcW[i];
  }
  __syncthreads();
  float y = fcb[lane];
  #pragma unroll 4
  for (int k = 0; k < 64; ++k){
    float hk = __shfl(h, k, 64);
    y += hk * fws[k * 64 + lane];
  }
  y = fmaxf(y, 0.f);
  if (c < NCC) comp0[c * 64 + lane] = y + emb[ids[c] * 64 + lane];
}

// ---------------- proj GEMM via MFMA: sent0 = bf16(sentence_x @ proj_W.T + b) ----------------
// BM=128, BN=64, BK=64. 4 waves, each computes 32 rows x 64 cols (2m x 4n frags of 16x16x32).
// A staged fp32->bf16 into XOR-swizzled LDS; B = proj_W rows ([n][k] row-major == Bt) likewise.
__global__ __launch_bounds__(256) void k_projm(const float* __restrict__ A, const float* __restrict__ W,
                                               const float* __restrict__ pb, u16* __restrict__ sent0){
  __shared__ __align__(16) u16 sA[128 * 64];  // 16 KB, byte ^= (row&7)<<4
  __shared__ __align__(16) u16 sB[64 * 64];   //  8 KB, [n][k] bf16, same swizzle
  char* sAb = (char*)sA;
  char* sBb = (char*)sB;
  int tid = threadIdx.x;
  int wave = tid >> 6, lane = tid & 63;
  int l15 = lane & 15, lg = lane >> 4;
  int s0 = blockIdx.x * 128;

  // staging coords
  int rA = tid >> 1, hA = tid & 1;            // A: row 0..127, k-half (32 floats)
  int sA_row = s0 + rA; if (sA_row >= SSN) sA_row = SSN - 1;
  const float* gA0 = &A[(size_t)sA_row * 768 + hA * 32];
  u32 aw_base = (u32)(rA * 128 + hA * 64);
  u32 aw_swz  = (u32)((rA & 7) << 4);
  int nB = tid >> 2, qB = tid & 3;            // B: n 0..63, k-quarter (16 floats)
  const float* gB0 = &W[(size_t)nB * 768 + qB * 16];
  u32 bw_base = (u32)(nB * 128 + qB * 32);
  u32 bw_swz  = (u32)((nB & 7) << 4);

  // fragment-read coords
  int arow = wave * 32 + l15;
  u32 ar_swz = (u32)((arow & 7) << 4);
  u32 ar_base = (u32)(arow * 128 + lg * 16);
  u32 br_swz = (u32)((l15 & 7) << 4);
  u32 br_base = (u32)(l15 * 128 + lg * 16);

  f32x4v acc[2][4] = {};

  for (int kc = 0; kc < 12; ++kc){
    __syncthreads();
    // stage A (8 float4 loads -> 4 x 16B swizzled LDS writes)
    {
      const float* g = gA0 + kc * 64;
      #pragma unroll
      for (int q = 0; q < 4; ++q){
        float4 va = ((const float4*)g)[2 * q];
        float4 vb = ((const float4*)g)[2 * q + 1];
        uint4 w;
        w.x = pk2(va.x, va.y); w.y = pk2(va.z, va.w);
        w.z = pk2(vb.x, vb.y); w.w = pk2(vb.z, vb.w);
        *(uint4*)(sAb + ((aw_base + q * 16) ^ aw_swz)) = w;
      }
    }
    // stage B (4 float4 loads -> 2 x 16B swizzled LDS writes)
    {
      const float* g = gB0 + kc * 64;
      #pragma unroll
      for (int q = 0; q < 2; ++q){
        float4 va = ((const float4*)g)[2 * q];
        float4 vb = ((const float4*)g)[2 * q + 1];
        uint4 w;
        w.x = pk2(va.x, va.y); w.y = pk2(va.z, va.w);
        w.z = pk2(vb.x, vb.y); w.w = pk2(vb.z, vb.w);
        *(uint4*)(sBb + ((bw_base + q * 16) ^ bw_swz)) = w;
      }
    }
    __syncthreads();
    #pragma unroll
    for (int ks = 0; ks < 2; ++ks){
      short8 a0 = *(const short8*)(sAb + ((ar_base + 0    + ks * 64) ^ ar_swz));
      short8 a1 = *(const short8*)(sAb + ((ar_base + 2048 + ks * 64) ^ ar_swz));
      short8 b0 = *(const short8*)(sBb + ((br_base + 0    + ks * 64) ^ br_swz));
      short8 b1 = *(const short8*)(sBb + ((br_base + 2048 + ks * 64) ^ br_swz));
      short8 b2 = *(const short8*)(sBb + ((br_base + 4096 + ks * 64) ^ br_swz));
      short8 b3 = *(const short8*)(sBb + ((br_base + 6144 + ks * 64) ^ br_swz));
      acc[0][0] = __builtin_amdgcn_mfma_f32_16x16x32_bf16(a0, b0, acc[0][0], 0, 0, 0);
      acc[0][1] = __builtin_amdgcn_mfma_f32_16x16x32_bf16(a0, b1, acc[0][1], 0, 0, 0);
      acc[0][2] = __builtin_amdgcn_mfma_f32_16x16x32_bf16(a0, b2, acc[0][2], 0, 0, 0);
      acc[0][3] = __builtin_amdgcn_mfma_f32_16x16x32_bf16(a0, b3, acc[0][3], 0, 0, 0);
      acc[1][0] = __builtin_amdgcn_mfma_f32_16x16x32_bf16(a1, b0, acc[1][0], 0, 0, 0);
      acc[1][1] = __builtin_amdgcn_mfma_f32_16x16x32_bf16(a1, b1, acc[1][1], 0, 0, 0);
      acc[1][2] = __builtin_amdgcn_mfma_f32_16x16x32_bf16(a1, b2, acc[1][2], 0, 0, 0);
      acc[1][3] = __builtin_amdgcn_mfma_f32_16x16x32_bf16(a1, b3, acc[1][3], 0, 0, 0);
    }
  }

  // epilogue: C row = wave*32 + mt*16 + lg*4 + j, col = nt*16 + l15
  float bias[4];
  #pragma unroll
  for (int nt = 0; nt < 4; ++nt) bias[nt] = pb[nt * 16 + l15];
  #pragma unroll
  for (int mt = 0; mt < 2; ++mt){
    #pragma unroll
    for (int j = 0; j < 4; ++j){
      int s = s0 + wave * 32 + mt * 16 + lg * 4 + j;
      if (s < SSN){
        #pragma unroll
        for (int nt = 0; nt < 4; ++nt)
          sent0[(size_t)s * 64 + nt * 16 + l15] = f2bf(acc[mt][nt][j] + bias[nt]);
      }
    }
  }
}

// ---------------- sentence GIN (in-place): sentOut = LReLU((sentIn + seg_sum(comp)) @ W.T + b) ----------------
__global__ __launch_bounds__(256) void k_sgin(const u16* __restrict__ sentIn, const float* __restrict__ compIn,
                                              const int* __restrict__ ofs, const int* __restrict__ bkt,
                                              const float* __restrict__ W, const float* __restrict__ b,
                                              const float* __restrict__ aP, u16* __restrict__ sentOut){
  __shared__ __align__(16) float Wt[64 * 68];
  __shared__ __align__(16) float Xt[64 * 68];
  int tid = threadIdx.x;
  for (int i = tid; i < 4096; i += 256){
    int j = i >> 6, k = i & 63;
    Wt[k * 68 + j] = W[i];
  }
  int wave = tid >> 6, lane = tid & 63;
  int sBase = blockIdx.x * 64;
  for (int q = 0; q < 16; ++q){
    int sL = wave * 16 + q;
    int s = sBase + sL;
    float acc = bf2f(sentIn[(size_t)s * 64 + lane]);
    int e0 = ofs[s], e1 = ofs[s + 1];
    for (int e = e0; e < e1; ++e){
      int src = bkt[e];
      acc += compIn[src * 64 + lane];
    }
    Xt[lane * 68 + sL] = acc;
  }
  __syncthreads();
  int n0 = (tid & 15) * 4, sG = (tid >> 4) * 4;
  float acc[4][4] = {};
  #pragma unroll 4
  for (int k = 0; k < 64; ++k){
    float4 a4 = *(const float4*)&Xt[k * 68 + sG];
    float4 w4 = *(const float4*)&Wt[k * 68 + n0];
    float a_[4] = {a4.x, a4.y, a4.z, a4.w};
    float w_[4] = {w4.x, w4.y, w4.z, w4.w};
    #pragma unroll
    for (int i = 0; i < 4; ++i)
      #pragma unroll
      for (int j = 0; j < 4; ++j)
        acc[i][j] += a_[i] * w_[j];
  }
  float alpha = *aP;
  float4 bv = *(const float4*)&b[n0];
  float b_[4] = {bv.x, bv.y, bv.z, bv.w};
  __syncthreads();  // all reads of sentIn rows done before in-place overwrite
  #pragma unroll
  for (int i = 0; i < 4; ++i){
    ushort4 o;
    #pragma unroll
    for (int j = 0; j < 4; ++j){
      float h = acc[i][j] + b_[j];
      h = (h >= 0.f) ? h : alpha * h;
      ((u16*)&o)[j] = f2bf(h);
    }
    *(ushort4*)&sentOut[(size_t)(sBase + sG + i) * 64 + n0] = o;
  }
}

// ---------------- company GIN (1024 threads = 16 waves for gather latency hiding) ----------------
__global__ __launch_bounds__(1024) void k_cgin(const float* __restrict__ compIn, const u16* __restrict__ sentIn,
                                               const int* __restrict__ ofsA, const int* __restrict__ bktA,
                                               const int* __restrict__ ofsB, const int* __restrict__ bktB,
                                               const float* __restrict__ Wa, const float* __restrict__ ba, const float* aaP,
                                               const float* __restrict__ Wb, const float* __restrict__ bb, const float* abP,
                                               float* __restrict__ compOut){
  __shared__ __align__(16) float Wat[64 * 68];
  __shared__ __align__(16) float Wbt[64 * 68];
  __shared__ float part[16][2][64];
  __shared__ float xa[64], xb[64], outab[128];
  int tid = threadIdx.x;
  for (int i = tid; i < 4096; i += 1024){
    int j = i >> 6, k = i & 63;
    Wat[k * 68 + j] = Wa[i];
    Wbt[k * 68 + j] = Wb[i];
  }
  int wave = tid >> 6, lane = tid & 63;
  int c = blockIdx.x;
  float accA = 0.f, accB = 0.f;
  int a0 = ofsA[c], a1 = ofsA[c + 1];
  for (int e = a0 + wave; e < a1; e += 16) accA += compIn[bktA[e] * 64 + lane];
  int b0 = ofsB[c], b1 = ofsB[c + 1];
  #pragma unroll 2
  for (int e = b0 + wave; e < b1; e += 16) accB += bf2f(sentIn[(size_t)bktB[e] * 64 + lane]);
  part[wave][0][lane] = accA;
  part[wave][1][lane] = accB;
  __syncthreads();
  if (tid < 128){
    int l = tid & 63, which = tid >> 6;
    float m = 0.f;
    #pragma unroll
    for (int w = 0; w < 16; ++w) m += part[w][which][l];
    float ci = compIn[c * 64 + l];
    if (which == 0) xa[l] = ci + m; else xb[l] = ci + m;
  }
  __syncthreads();
  if (tid < 128){
    int j = tid & 63;
    const float* X  = (tid < 64) ? xa : xb;
    const float* Wt = (tid < 64) ? Wat : Wbt;
    float acc = (tid < 64) ? ba[j] : bb[j];
    #pragma unroll 4
    for (int k = 0; k < 64; ++k) acc += X[k] * Wt[k * 68 + j];
    float al = (tid < 64) ? *aaP : *abP;
    outab[tid] = (acc >= 0.f) ? acc : al * acc;
  }
  __syncthreads();
  if (tid < 64) compOut[c * 64 + tid] = outab[tid] + outab[64 + tid];
}

// ---------------- final classifier ----------------
__global__ __launch_bounds__(256) void k_cls(const float* __restrict__ comp, const float* __restrict__ W,
                                             const float* __restrict__ b, float* __restrict__ outp){
  int i = blockIdx.x * 256 + threadIdx.x;
  if (i >= NCC * 2) return;
  int c = i >> 1, j = i & 1;
  float acc = b[j];
  #pragma unroll 4
  for (int k = 0; k < 64; ++k) acc += comp[c * 64 + k] * W[j * 64 + k];
  outp[i] = acc;
}

extern "C" void kernel_launch(void* const* d_in, const int* in_sizes, int n_in,
                              void* d_out, int out_size, void* d_ws, size_t ws_size,
                              hipStream_t stream) {
  (void)in_sizes; (void)n_in; (void)out_size; (void)ws_size;
  const float* company_ts = (const float*)d_in[0];
  const float* sentence_x = (const float*)d_in[1];
  const int*   company_ids = (const int*)d_in[2];
  const int*   c2c_src = (const int*)d_in[3];
  const int*   c2c_dst = (const int*)d_in[4];
  const int*   s2c_src = (const int*)d_in[5];
  const int*   s2c_dst = (const int*)d_in[6];
  const int*   c2s_src = (const int*)d_in[7];
  const int*   c2s_dst = (const int*)d_in[8];
  const float* bn_gamma = (const float*)d_in[9];
  const float* bn_beta  = (const float*)d_in[10];
  const float* Wih0 = (const float*)d_in[11];
  const float* Whh0 = (const float*)d_in[12];
  const float* bih0 = (const float*)d_in[13];
  const float* bhh0 = (const float*)d_in[14];
  const float* Wih1 = (const float*)d_in[15];
  const float* Whh1 = (const float*)d_in[16];
  const float* bih1 = (const float*)d_in[17];
  const float* bhh1 = (const float*)d_in[18];
  const float* fc_W = (const float*)d_in[19];
  const float* fc_b = (const float*)d_in[20];
  const float* comp_emb = (const float*)d_in[21];
  const float* proj_W = (const float*)d_in[22];
  const float* proj_b = (const float*)d_in[23];
  const float* gin_W = (const float*)d_in[24];
  const float* gin_b = (const float*)d_in[25];
  const float* gin_a = (const float*)d_in[26];
  const float* cls_W = (const float*)d_in[27];
  const float* cls_b = (const float*)d_in[28];
  float* outp = (float*)d_out;

  char* ws = (char*)d_ws;
  size_t off = 0;
  auto alloc = [&](size_t bytes)->char* {
    char* r = ws + off;
    off += (bytes + 255) & ~(size_t)255;
    return r;
  };
  float* ts_norm = (float*)alloc((size_t)NCC * TTT * 4);
  float* h0seq   = (float*)alloc((size_t)NCC * TTT * 64 * 4);
  float* comp0   = (float*)alloc((size_t)NCC * 64 * 4);
  float* comp1   = (float*)alloc((size_t)NCC * 64 * 4);
  float* comp2   = (float*)alloc((size_t)NCC * 64 * 4);
  u16*   sent0   = (u16*)alloc((size_t)SSN * 64 * 2);   // reused in place as sent1
  int*   blockHist = (int*)alloc((size_t)NCC * NB2 * 4);   // [d][b]
  int*   colTotal  = (int*)alloc((size_t)NCC * 4);
  int*   cnt_c2c  = (int*)alloc((size_t)(NCC + NCC + SSN + SSN) * 4);
  int*   cnt2_c2c = cnt_c2c + NCC;
  int*   cnt_c2s  = cnt2_c2c + NCC;
  int*   cnt2_c2s = cnt_c2s + SSN;
  int*   off_c2c = (int*)alloc((size_t)(NCC + 1) * 4);
  int*   off_s2c = (int*)alloc((size_t)(NCC + 1) * 4);
  int*   off_c2s = (int*)alloc((size_t)(SSN + 1) * 4);
  int*   bkt_c2c = (int*)alloc((size_t)ECN * 4);
  int*   bkt_s2c = (int*)alloc((size_t)EEN * 4);
  int*   bkt_c2s = (int*)alloc((size_t)EEN * 4);
  int*   bsum    = (int*)alloc(256 * 4);
  int*   boff    = (int*)alloc(257 * 4);

  const int ZN = NCC + NCC + SSN + SSN;

  // --- CSR builds ---
  k_zero<<<(ZN + 255) / 256, 256, 0, stream>>>(cnt_c2c, ZN);
  k_hist2<<<NB2, 256, 0, stream>>>(s2c_dst, blockHist);
  k_hist_all<<<(ECN + EEN + 255) / 256, 256, 0, stream>>>(c2c_dst, ECN, cnt_c2c, c2s_dst, EEN, cnt_c2s);
  k_colscan<<<NCC, 64, 0, stream>>>(blockHist, colTotal);
  k_scan_small<<<1, 1024, 0, stream>>>(colTotal, off_s2c, NCC);
  k_scan_small<<<1, 1024, 0, stream>>>(cnt_c2c, off_c2c, NCC);
  k_scan_blocks<<<CSBLK, 1024, 0, stream>>>(cnt_c2s, off_c2s, SSN, bsum);
  k_scan_small<<<1, 1024, 0, stream>>>(bsum, boff, CSBLK);
  k_scan_add<<<CSBLK, 1024, 0, stream>>>(off_c2s, boff, SSN, CSBLK);
  k_scatter2<<<NB2, 256, 0, stream>>>(s2c_src, s2c_dst, blockHist, off_s2c, bkt_s2c);
  k_scatter_all<<<(ECN + EEN + 255) / 256, 256, 0, stream>>>(
      c2c_src, c2c_dst, off_c2c, cnt2_c2c, bkt_c2c, ECN,
      c2s_src, c2s_dst, off_c2s, cnt2_c2s, bkt_c2s, EEN);

  // --- time-series branch ---
  k_bn<<<TTT, 256, 0, stream>>>(company_ts, bn_gamma, bn_beta, ts_norm);
  k_lstm0<<<(NCC + 3) / 4, 256, 0, stream>>>(ts_norm, Wih0, Whh0, bih0, bhh0, h0seq);
  k_lstm1<<<(NCC + 3) / 4, 256, 0, stream>>>(h0seq, Wih1, Whh1, bih1, bhh1, fc_W, fc_b,
                                             comp_emb, company_ids, comp0);

  // --- sentence projection (MFMA) ---
  k_projm<<<(SSN + 127) / 128, 256, 0, stream>>>(sentence_x, proj_W, proj_b, sent0);

  // --- GIN layer 0 ---
  k_cgin<<<NCC, 1024, 0, stream>>>(comp0, sent0,
                                   off_c2c, bkt_c2c, off_s2c, bkt_s2c,
                                   gin_W + 0 * 4096, gin_b + 0 * 64, gin_a + 0,
                                   gin_W + 1 * 4096, gin_b + 1 * 64, gin_a + 1,
                                   comp1);
  k_sgin<<<SSN / 64, 256, 0, stream>>>(sent0, comp0, off_c2s, bkt_c2s,
                                       gin_W + 2 * 4096, gin_b + 2 * 64, gin_a + 2,
                                       sent0 /* in place */);

  // --- GIN layer 1 (new_sent of layer 1 is dead code) ---
  k_cgin<<<NCC, 1024, 0, stream>>>(comp1, sent0,
                                   off_c2c, bkt_c2c, off_s2c, bkt_s2c,
                                   gin_W + 3 * 4096, gin_b + 3 * 64, gin_a + 3,
                                   gin_W + 4 * 4096, gin_b + 4 * 64, gin_a + 4,
                                   comp2);

  // --- classifier ---
  k_cls<<<(NCC * 2 + 255) / 256, 256, 0, stream>>>(comp2, cls_W, cls_b, outp);
}

// Round 4
// 687.141 us; speedup vs baseline: 2.3171x; 1.1639x over previous
//
#include <hip/hip_runtime.h>

#define NCC 617
#define TTT 15
#define FFF 5
#define SSN 200000
#define EEN 1000000
#define ECN 20000
#define CSBLK 196   /* ceil(SSN/1024) */
#define NB2 512
#define EPB2 ((EEN + NB2 - 1) / NB2)   /* 1954 */
#define ZN (NCC + NCC + SSN + SSN)

typedef unsigned short u16;
typedef unsigned int   u32;

using short8  = __attribute__((ext_vector_type(8))) short;
using f32x4v  = __attribute__((ext_vector_type(4))) float;

__device__ __forceinline__ float bf2f(u16 u){ return __uint_as_float(((u32)u) << 16); }
__device__ __forceinline__ u16 f2bf(float f){
  u32 x = __float_as_uint(f);
  u32 r = (x + 0x7fffu + ((x >> 16) & 1u)) >> 16;
  return (u16)r;
}
__device__ __forceinline__ u32 pk2(float a, float b){ return (u32)f2bf(a) | ((u32)f2bf(b) << 16); }
__device__ __forceinline__ float sigm(float x){ return 1.0f / (1.0f + __expf(-x)); }

// ---------------- s2c block-hist + zero all global counters ----------------
__global__ __launch_bounds__(256) void k_hist2z(const int* __restrict__ dst, int* __restrict__ blockHist,
                                                int* __restrict__ cntBase){
  __shared__ int h[NCC];
  int b = blockIdx.x, tid = threadIdx.x;
  // zero the shared counter block (ZN ints over NB2 blocks)
  const int zper = (ZN + NB2 - 1) / NB2;
  for (int i = tid; i < zper; i += 256){
    int gi = b * zper + i;
    if (gi < ZN) cntBase[gi] = 0;
  }
  for (int i = tid; i < NCC; i += 256) h[i] = 0;
  __syncthreads();
  int e0 = b * EPB2;
  int e1 = e0 + EPB2; if (e1 > EEN) e1 = EEN;
  for (int e = e0 + tid; e < e1; e += 256) atomicAdd(&h[dst[e]], 1);
  __syncthreads();
  for (int i = tid; i < NCC; i += 256) blockHist[i * NB2 + b] = h[i];
}

// combined histogram for c2c (20k edges) and c2s (200k counters, low contention)
__global__ __launch_bounds__(256) void k_hist_all(const int* d1, int n1, int* c1,
                                                  const int* d2, int n2, int* c2){
  int i = blockIdx.x * 256 + threadIdx.x;
  if (i < n1) atomicAdd(&c1[d1[i]], 1);
  else if (i < n1 + n2) atomicAdd(&c2[d2[i - n1]], 1);
}

__global__ __launch_bounds__(64) void k_colscan(int* __restrict__ blockHist, int* __restrict__ colTotal){
  int d = blockIdx.x, lane = threadIdx.x;
  int base = 0;
  for (int j = 0; j < NB2; j += 64){
    int v = blockHist[d * NB2 + j + lane];
    int orig = v;
    #pragma unroll
    for (int s = 1; s < 64; s <<= 1){
      int t = __shfl_up(v, s, 64);
      if (lane >= s) v += t;
    }
    blockHist[d * NB2 + j + lane] = base + v - orig;   // exclusive within column
    base += __shfl(v, 63, 64);
  }
  if (lane == 0) colTotal[d] = base;
}

// dual 617-length exclusive scan in one launch (single block)
__global__ __launch_bounds__(1024) void k_scan2(const int* cntA, int* ofsA,
                                                const int* cntB, int* ofsB, int n){
  __shared__ int buf[1024];
  int t = threadIdx.x;
  for (int pass = 0; pass < 2; ++pass){
    const int* cnt = pass ? cntB : cntA;
    int* ofs = pass ? ofsB : ofsA;
    int v = (t < n) ? cnt[t] : 0;
    buf[t] = v;
    __syncthreads();
    for (int d = 1; d < 1024; d <<= 1){
      int x = (t >= d) ? buf[t - d] : 0;
      __syncthreads();
      buf[t] += x;
      __syncthreads();
    }
    if (t < n) ofs[t] = (t == 0) ? 0 : buf[t - 1];
    if (t == 0) ofs[n] = buf[n - 1];
    __syncthreads();
  }
}

__global__ __launch_bounds__(1024) void k_scan_blocks(const int* cnt, int* ofs, int n, int* bsum){
  __shared__ int buf[1024];
  int t = threadIdx.x;
  int gi = blockIdx.x * 1024 + t;
  int v = (gi < n) ? cnt[gi] : 0;
  buf[t] = v;
  __syncthreads();
  for (int d = 1; d < 1024; d <<= 1){
    int x = (t >= d) ? buf[t - d] : 0;
    __syncthreads();
    buf[t] += x;
    __syncthreads();
  }
  if (gi < n) ofs[gi] = buf[t] - v;   // exclusive within block
  if (t == 1023) bsum[blockIdx.x] = buf[1023];
}

// every block redundantly scans the 196 block sums (wave 0), then adds its offset
__global__ __launch_bounds__(1024) void k_scan_addB(int* __restrict__ ofs, const int* __restrict__ bsum, int n){
  __shared__ int sboff[CSBLK + 1];
  int tid = threadIdx.x, lane = tid & 63;
  if (tid < 64){
    int base = 0;
    for (int j = 0; j < CSBLK; j += 64){
      int idx = j + lane;
      int v = (idx < CSBLK) ? bsum[idx] : 0;
      int orig = v;
      #pragma unroll
      for (int s = 1; s < 64; s <<= 1){
        int t2 = __shfl_up(v, s, 64);
        if (lane >= s) v += t2;
      }
      if (idx < CSBLK) sboff[idx] = base + v - orig;
      base += __shfl(v, 63, 64);
    }
    if (lane == 0) sboff[CSBLK] = base;
  }
  __syncthreads();
  int gi = blockIdx.x * 1024 + tid;
  if (gi < n) ofs[gi] += sboff[blockIdx.x];
  if (blockIdx.x == 0 && tid == 0) ofs[n] = sboff[CSBLK];
}

__global__ __launch_bounds__(256) void k_scatter2(const int* __restrict__ src, const int* __restrict__ dst,
                                                  const int* __restrict__ blockHist, const int* __restrict__ off,
                                                  int* __restrict__ bkt){
  __shared__ int cur[NCC];
  int b = blockIdx.x, tid = threadIdx.x;
  for (int i = tid; i < NCC; i += 256) cur[i] = off[i] + blockHist[i * NB2 + b];
  __syncthreads();
  int e0 = b * EPB2;
  int e1 = e0 + EPB2; if (e1 > EEN) e1 = EEN;
  for (int e = e0 + tid; e < e1; e += 256){
    int d = dst[e];
    int p = atomicAdd(&cur[d], 1);
    bkt[p] = src[e];
  }
}

__global__ __launch_bounds__(256) void k_scatter_all(const int* s1, const int* d1, const int* off1, int* cnt1, int* bkt1, int n1,
                                                     const int* s2, const int* d2, const int* off2, int* cnt2, int* bkt2, int n2){
  int i = blockIdx.x * 256 + threadIdx.x;
  if (i < n1){
    int d = d1[i]; int p = off1[d] + atomicAdd(&cnt1[d], 1); bkt1[p] = s1[i];
  } else if (i < n1 + n2){
    int k = i - n1;
    int d = d2[k]; int p = off2[d] + atomicAdd(&cnt2[d], 1); bkt2[p] = s2[k];
  }
}

// ---------------- batchnorm over companies per timestep ----------------
__global__ __launch_bounds__(256) void k_bn(const float* ts, const float* gamma, const float* beta, float* outp){
  __shared__ float ss[256], s2[256];
  int t = blockIdx.x, tid = threadIdx.x;
  float a = 0.f, b = 0.f;
  for (int c = tid; c < NCC; c += 256){
    float v = ts[(c * TTT + t) * FFF + 3];
    a += v; b += v * v;
  }
  ss[tid] = a; s2[tid] = b;
  __syncthreads();
  for (int d = 128; d > 0; d >>= 1){
    if (tid < d){ ss[tid] += ss[tid + d]; s2[tid] += s2[tid + d]; }
    __syncthreads();
  }
  float mean = ss[0] / (float)NCC;
  float var  = s2[0] / (float)NCC - mean * mean;
  float rstd = rsqrtf(var + 1e-5f);
  float g = gamma[t], be = beta[t];
  for (int c = tid; c < NCC; c += 256){
    float v = ts[(c * TTT + t) * FFF + 3];
    outp[c * TTT + t] = (v - mean) * rstd * g + be;
  }
}

// ---------------- LSTM layer 0 (input dim 1) ----------------
__global__ __launch_bounds__(256) void k_lstm0(const float* tsn, const float* Wih0, const float* Whh0,
                                               const float* bih0, const float* bhh0, float* h0seq){
  __shared__ __align__(16) u16 sW[64 * 256];  // [k][j] bf16 of Whh0^T
  __shared__ float sWi[256];
  __shared__ float sB[256];
  int tid = threadIdx.x;
  for (int i = tid; i < 64 * 256; i += 256){
    int j = i >> 6, k = i & 63;
    sW[k * 256 + j] = f2bf(Whh0[i]);
  }
  if (tid < 256){ sWi[tid] = Wih0[tid]; sB[tid] = bih0[tid] + bhh0[tid]; }
  __syncthreads();
  int wave = tid >> 6, lane = tid & 63;
  int c = blockIdx.x * 4 + wave;
  if (c >= NCC) return;
  float wi_i = sWi[lane], wi_f = sWi[64 + lane], wi_g = sWi[128 + lane], wi_o = sWi[192 + lane];
  float b_i = sB[lane], b_f = sB[64 + lane], b_g = sB[128 + lane], b_o = sB[192 + lane];
  float h = 0.f, cs = 0.f;
  for (int t = 0; t < TTT; ++t){
    float x = tsn[c * TTT + t];
    float gi = b_i + x * wi_i, gf = b_f + x * wi_f, gg = b_g + x * wi_g, go = b_o + x * wi_o;
    #pragma unroll 4
    for (int k = 0; k < 64; ++k){
      float hk = __shfl(h, k, 64);
      const u16* w = &sW[k * 256 + lane];
      gi += hk * bf2f(w[0]);
      gf += hk * bf2f(w[64]);
      gg += hk * bf2f(w[128]);
      go += hk * bf2f(w[192]);
    }
    cs = sigm(gf) * cs + sigm(gi) * tanhf(gg);
    h  = sigm(go) * tanhf(cs);
    h0seq[(c * TTT + t) * 64 + lane] = h;
  }
}

// ---------------- LSTM layer 1 + fc + emb ----------------
__global__ __launch_bounds__(256, 1) void k_lstm1(const float* h0seq, const float* Wih1, const float* Whh1,
                                                  const float* bih1, const float* bhh1,
                                                  const float* fcW, const float* fcb,
                                                  const float* emb, const int* ids, float* comp0){
  __shared__ __align__(16) u16 sWi[64 * 256];
  __shared__ __align__(16) u16 sWh[64 * 256];
  int tid = threadIdx.x;
  for (int i = tid; i < 64 * 256; i += 256){
    int j = i >> 6, k = i & 63;
    sWi[k * 256 + j] = f2bf(Wih1[i]);
    sWh[k * 256 + j] = f2bf(Whh1[i]);
  }
  __syncthreads();
  int wave = tid >> 6, lane = tid & 63;
  int c = blockIdx.x * 4 + wave;
  int ci = (c < NCC) ? c : (NCC - 1);
  float b_i = bih1[lane]        + bhh1[lane];
  float b_f = bih1[64 + lane]   + bhh1[64 + lane];
  float b_g = bih1[128 + lane]  + bhh1[128 + lane];
  float b_o = bih1[192 + lane]  + bhh1[192 + lane];
  float h = 0.f, cs = 0.f;
  for (int t = 0; t < TTT; ++t){
    float x = h0seq[(ci * TTT + t) * 64 + lane];
    float gi = b_i, gf = b_f, gg = b_g, go = b_o;
    #pragma unroll 4
    for (int k = 0; k < 64; ++k){
      float xk = __shfl(x, k, 64);
      float hk = __shfl(h, k, 64);
      const u16* wi = &sWi[k * 256 + lane];
      const u16* wh = &sWh[k * 256 + lane];
      gi += xk * bf2f(wi[0])   + hk * bf2f(wh[0]);
      gf += xk * bf2f(wi[64])  + hk * bf2f(wh[64]);
      gg += xk * bf2f(wi[128]) + hk * bf2f(wh[128]);
      go += xk * bf2f(wi[192]) + hk * bf2f(wh[192]);
    }
    cs = sigm(gf) * cs + sigm(gi) * tanhf(gg);
    h  = sigm(go) * tanhf(cs);
  }
  __syncthreads();
  float* fws = (float*)sWi;
  for (int i = tid; i < 64 * 64; i += 256){
    int d = i >> 6, k = i & 63;
    fws[k * 64 + d] = fcW[i];
  }
  __syncthreads();
  float y = fcb[lane];
  #pragma unroll 4
  for (int k = 0; k < 64; ++k){
    float hk = __shfl(h, k, 64);
    y += hk * fws[k * 64 + lane];
  }
  y = fmaxf(y, 0.f);
  if (c < NCC) comp0[c * 64 + lane] = y + emb[ids[c] * 64 + lane];
}

// ---------------- proj GEMM via MFMA ----------------
__global__ __launch_bounds__(256) void k_projm(const float* __restrict__ A, const float* __restrict__ W,
                                               const float* __restrict__ pb, u16* __restrict__ sent0){
  __shared__ __align__(16) u16 sA[128 * 64];  // 16 KB, byte ^= (row&7)<<4
  __shared__ __align__(16) u16 sB[64 * 64];   //  8 KB
  char* sAb = (char*)sA;
  char* sBb = (char*)sB;
  int tid = threadIdx.x;
  int wave = tid >> 6, lane = tid & 63;
  int l15 = lane & 15, lg = lane >> 4;
  int s0 = blockIdx.x * 128;

  int rA = tid >> 1, hA = tid & 1;
  int sA_row = s0 + rA; if (sA_row >= SSN) sA_row = SSN - 1;
  const float* gA0 = &A[(size_t)sA_row * 768 + hA * 32];
  u32 aw_base = (u32)(rA * 128 + hA * 64);
  u32 aw_swz  = (u32)((rA & 7) << 4);
  int nB = tid >> 2, qB = tid & 3;
  const float* gB0 = &W[(size_t)nB * 768 + qB * 16];
  u32 bw_base = (u32)(nB * 128 + qB * 32);
  u32 bw_swz  = (u32)((nB & 7) << 4);

  int arow = wave * 32 + l15;
  u32 ar_swz = (u32)((arow & 7) << 4);
  u32 ar_base = (u32)(arow * 128 + lg * 16);
  u32 br_swz = (u32)((l15 & 7) << 4);
  u32 br_base = (u32)(l15 * 128 + lg * 16);

  f32x4v acc[2][4] = {};

  for (int kc = 0; kc < 12; ++kc){
    __syncthreads();
    {
      const float* g = gA0 + kc * 64;
      #pragma unroll
      for (int q = 0; q < 4; ++q){
        float4 va = ((const float4*)g)[2 * q];
        float4 vb = ((const float4*)g)[2 * q + 1];
        uint4 w;
        w.x = pk2(va.x, va.y); w.y = pk2(va.z, va.w);
        w.z = pk2(vb.x, vb.y); w.w = pk2(vb.z, vb.w);
        *(uint4*)(sAb + ((aw_base + q * 16) ^ aw_swz)) = w;
      }
    }
    {
      const float* g = gB0 + kc * 64;
      #pragma unroll
      for (int q = 0; q < 2; ++q){
        float4 va = ((const float4*)g)[2 * q];
        float4 vb = ((const float4*)g)[2 * q + 1];
        uint4 w;
        w.x = pk2(va.x, va.y); w.y = pk2(va.z, va.w);
        w.z = pk2(vb.x, vb.y); w.w = pk2(vb.z, vb.w);
        *(uint4*)(sBb + ((bw_base + q * 16) ^ bw_swz)) = w;
      }
    }
    __syncthreads();
    #pragma unroll
    for (int ks = 0; ks < 2; ++ks){
      short8 a0 = *(const short8*)(sAb + ((ar_base + 0    + ks * 64) ^ ar_swz));
      short8 a1 = *(const short8*)(sAb + ((ar_base + 2048 + ks * 64) ^ ar_swz));
      short8 b0 = *(const short8*)(sBb + ((br_base + 0    + ks * 64) ^ br_swz));
      short8 b1 = *(const short8*)(sBb + ((br_base + 2048 + ks * 64) ^ br_swz));
      short8 b2 = *(const short8*)(sBb + ((br_base + 4096 + ks * 64) ^ br_swz));
      short8 b3 = *(const short8*)(sBb + ((br_base + 6144 + ks * 64) ^ br_swz));
      acc[0][0] = __builtin_amdgcn_mfma_f32_16x16x32_bf16(a0, b0, acc[0][0], 0, 0, 0);
      acc[0][1] = __builtin_amdgcn_mfma_f32_16x16x32_bf16(a0, b1, acc[0][1], 0, 0, 0);
      acc[0][2] = __builtin_amdgcn_mfma_f32_16x16x32_bf16(a0, b2, acc[0][2], 0, 0, 0);
      acc[0][3] = __builtin_amdgcn_mfma_f32_16x16x32_bf16(a0, b3, acc[0][3], 0, 0, 0);
      acc[1][0] = __builtin_amdgcn_mfma_f32_16x16x32_bf16(a1, b0, acc[1][0], 0, 0, 0);
      acc[1][1] = __builtin_amdgcn_mfma_f32_16x16x32_bf16(a1, b1, acc[1][1], 0, 0, 0);
      acc[1][2] = __builtin_amdgcn_mfma_f32_16x16x32_bf16(a1, b2, acc[1][2], 0, 0, 0);
      acc[1][3] = __builtin_amdgcn_mfma_f32_16x16x32_bf16(a1, b3, acc[1][3], 0, 0, 0);
    }
  }

  float bias[4];
  #pragma unroll
  for (int nt = 0; nt < 4; ++nt) bias[nt] = pb[nt * 16 + l15];
  #pragma unroll
  for (int mt = 0; mt < 2; ++mt){
    #pragma unroll
    for (int j = 0; j < 4; ++j){
      int s = s0 + wave * 32 + mt * 16 + lg * 4 + j;
      if (s < SSN){
        #pragma unroll
        for (int nt = 0; nt < 4; ++nt)
          sent0[(size_t)s * 64 + nt * 16 + l15] = f2bf(acc[mt][nt][j] + bias[nt]);
      }
    }
  }
}

// ---------------- sentence GIN (in-place), LDS-staged edge indices ----------------
__global__ __launch_bounds__(256) void k_sgin(const u16* __restrict__ sentIn, const float* __restrict__ compIn,
                                              const int* __restrict__ ofs, const int* __restrict__ bkt,
                                              const float* __restrict__ W, const float* __restrict__ b,
                                              const float* __restrict__ aP, u16* __restrict__ sentOut){
  __shared__ __align__(16) float Wt[64 * 68];
  __shared__ __align__(16) float Xt[64 * 68];
  __shared__ int eb[512];
  __shared__ int sofs[65];
  int tid = threadIdx.x;
  for (int i = tid; i < 4096; i += 256){
    int j = i >> 6, k = i & 63;
    Wt[k * 68 + j] = W[i];
  }
  int sBase = blockIdx.x * 64;
  if (tid < 65) sofs[tid] = ofs[sBase + tid];
  __syncthreads();
  int E0 = sofs[0];
  int tot = sofs[64] - E0;
  int staged = tot < 512 ? tot : 512;
  for (int i = tid; i < staged; i += 256) eb[i] = bkt[E0 + i];
  __syncthreads();
  int wave = tid >> 6, lane = tid & 63;
  for (int q = 0; q < 16; ++q){
    int sL = wave * 16 + q;
    int s = sBase + sL;
    float acc = bf2f(sentIn[(size_t)s * 64 + lane]);
    int e0 = sofs[sL], e1 = sofs[sL + 1];
    for (int e = e0; e < e1; ++e){
      int r = e - E0;
      int src = (r < 512) ? eb[r] : bkt[e];
      acc += compIn[src * 64 + lane];
    }
    Xt[lane * 68 + sL] = acc;
  }
  __syncthreads();
  int n0 = (tid & 15) * 4, sG = (tid >> 4) * 4;
  float acc[4][4] = {};
  #pragma unroll 4
  for (int k = 0; k < 64; ++k){
    float4 a4 = *(const float4*)&Xt[k * 68 + sG];
    float4 w4 = *(const float4*)&Wt[k * 68 + n0];
    float a_[4] = {a4.x, a4.y, a4.z, a4.w};
    float w_[4] = {w4.x, w4.y, w4.z, w4.w};
    #pragma unroll
    for (int i = 0; i < 4; ++i)
      #pragma unroll
      for (int j = 0; j < 4; ++j)
        acc[i][j] += a_[i] * w_[j];
  }
  float alpha = *aP;
  float4 bv = *(const float4*)&b[n0];
  float b_[4] = {bv.x, bv.y, bv.z, bv.w};
  __syncthreads();  // all sentIn reads done before in-place overwrite
  #pragma unroll
  for (int i = 0; i < 4; ++i){
    ushort4 o;
    #pragma unroll
    for (int j = 0; j < 4; ++j){
      float h = acc[i][j] + b_[j];
      h = (h >= 0.f) ? h : alpha * h;
      ((u16*)&o)[j] = f2bf(h);
    }
    *(ushort4*)&sentOut[(size_t)(sBase + sG + i) * 64 + n0] = o;
  }
}

// ---------------- company GIN, LDS-staged edge indices; optional fused classifier ----------------
__global__ __launch_bounds__(1024) void k_cgin(const float* __restrict__ compIn, const u16* __restrict__ sentIn,
                                               const int* __restrict__ ofsA, const int* __restrict__ bktA,
                                               const int* __restrict__ ofsB, const int* __restrict__ bktB,
                                               const float* __restrict__ Wa, const float* __restrict__ ba, const float* aaP,
                                               const float* __restrict__ Wb, const float* __restrict__ bb, const float* abP,
                                               float* __restrict__ compOut,
                                               const float* __restrict__ clsW, const float* __restrict__ clsb,
                                               float* __restrict__ outp){
  __shared__ __align__(16) float Wat[64 * 68];
  __shared__ __align__(16) float Wbt[64 * 68];
  __shared__ int eidx[2048];
  __shared__ float part[16][2][64];
  __shared__ float xa[64], xb[64], outab[128];
  int tid = threadIdx.x;
  for (int i = tid; i < 4096; i += 1024){
    int j = i >> 6, k = i & 63;
    Wat[k * 68 + j] = Wa[i];
    Wbt[k * 68 + j] = Wb[i];
  }
  int wave = tid >> 6, lane = tid & 63;
  int c = blockIdx.x;
  float accA = 0.f, accB = 0.f;
  int a0 = ofsA[c], a1 = ofsA[c + 1];
  for (int base = a0; base < a1; base += 2048){
    int cnt = a1 - base; if (cnt > 2048) cnt = 2048;
    __syncthreads();
    for (int i = tid; i < cnt; i += 1024) eidx[i] = bktA[base + i];
    __syncthreads();
    for (int i = wave; i < cnt; i += 16) accA += compIn[eidx[i] * 64 + lane];
  }
  int b0 = ofsB[c], b1 = ofsB[c + 1];
  for (int base = b0; base < b1; base += 2048){
    int cnt = b1 - base; if (cnt > 2048) cnt = 2048;
    __syncthreads();
    for (int i = tid; i < cnt; i += 1024) eidx[i] = bktB[base + i];
    __syncthreads();
    #pragma unroll 4
    for (int i = wave; i < cnt; i += 16) accB += bf2f(sentIn[(size_t)eidx[i] * 64 + lane]);
  }
  part[wave][0][lane] = accA;
  part[wave][1][lane] = accB;
  __syncthreads();
  if (tid < 128){
    int l = tid & 63, which = tid >> 6;
    float m = 0.f;
    #pragma unroll
    for (int w = 0; w < 16; ++w) m += part[w][which][l];
    float ci = compIn[c * 64 + l];
    if (which == 0) xa[l] = ci + m; else xb[l] = ci + m;
  }
  __syncthreads();
  if (tid < 128){
    int j = tid & 63;
    const float* X  = (tid < 64) ? xa : xb;
    const float* Wt = (tid < 64) ? Wat : Wbt;
    float acc = (tid < 64) ? ba[j] : bb[j];
    #pragma unroll 4
    for (int k = 0; k < 64; ++k) acc += X[k] * Wt[k * 68 + j];
    float al = (tid < 64) ? *aaP : *abP;
    outab[tid] = (acc >= 0.f) ? acc : al * acc;
  }
  __syncthreads();
  if (clsW){
    if (tid < 64) xa[tid] = outab[tid] + outab[64 + tid];
    __syncthreads();
    if (tid < 128){
      int j = tid >> 6;
      float p = xa[lane] * clsW[j * 64 + lane];
      #pragma unroll
      for (int s = 32; s > 0; s >>= 1) p += __shfl_down(p, s, 64);
      if (lane == 0) outp[c * 2 + j] = p + clsb[j];
    }
  } else {
    if (tid < 64) compOut[c * 64 + tid] = outab[tid] + outab[64 + tid];
  }
}

extern "C" void kernel_launch(void* const* d_in, const int* in_sizes, int n_in,
                              void* d_out, int out_size, void* d_ws, size_t ws_size,
                              hipStream_t stream) {
  (void)in_sizes; (void)n_in; (void)out_size; (void)ws_size;
  const float* company_ts = (const float*)d_in[0];
  const float* sentence_x = (const float*)d_in[1];
  const int*   company_ids = (const int*)d_in[2];
  const int*   c2c_src = (const int*)d_in[3];
  const int*   c2c_dst = (const int*)d_in[4];
  const int*   s2c_src = (const int*)d_in[5];
  const int*   s2c_dst = (const int*)d_in[6];
  const int*   c2s_src = (const int*)d_in[7];
  const int*   c2s_dst = (const int*)d_in[8];
  const float* bn_gamma = (const float*)d_in[9];
  const float* bn_beta  = (const float*)d_in[10];
  const float* Wih0 = (const float*)d_in[11];
  const float* Whh0 = (const float*)d_in[12];
  const float* bih0 = (const float*)d_in[13];
  const float* bhh0 = (const float*)d_in[14];
  const float* Wih1 = (const float*)d_in[15];
  const float* Whh1 = (const float*)d_in[16];
  const float* bih1 = (const float*)d_in[17];
  const float* bhh1 = (const float*)d_in[18];
  const float* fc_W = (const float*)d_in[19];
  const float* fc_b = (const float*)d_in[20];
  const float* comp_emb = (const float*)d_in[21];
  const float* proj_W = (const float*)d_in[22];
  const float* proj_b = (const float*)d_in[23];
  const float* gin_W = (const float*)d_in[24];
  const float* gin_b = (const float*)d_in[25];
  const float* gin_a = (const float*)d_in[26];
  const float* cls_W = (const float*)d_in[27];
  const float* cls_b = (const float*)d_in[28];
  float* outp = (float*)d_out;

  char* ws = (char*)d_ws;
  size_t off = 0;
  auto alloc = [&](size_t bytes)->char* {
    char* r = ws + off;
    off += (bytes + 255) & ~(size_t)255;
    return r;
  };
  float* ts_norm = (float*)alloc((size_t)NCC * TTT * 4);
  float* h0seq   = (float*)alloc((size_t)NCC * TTT * 64 * 4);
  float* comp0   = (float*)alloc((size_t)NCC * 64 * 4);
  float* comp1   = (float*)alloc((size_t)NCC * 64 * 4);
  u16*   sent0   = (u16*)alloc((size_t)SSN * 64 * 2);   // reused in place as sent1
  int*   blockHist = (int*)alloc((size_t)NCC * NB2 * 4);   // [d][b]
  int*   colTotal  = (int*)alloc((size_t)NCC * 4);
  int*   cnt_c2c  = (int*)alloc((size_t)ZN * 4);
  int*   cnt2_c2c = cnt_c2c + NCC;
  int*   cnt_c2s  = cnt2_c2c + NCC;
  int*   cnt2_c2s = cnt_c2s + SSN;
  int*   off_c2c = (int*)alloc((size_t)(NCC + 1) * 4);
  int*   off_s2c = (int*)alloc((size_t)(NCC + 1) * 4);
  int*   off_c2s = (int*)alloc((size_t)(SSN + 1) * 4);
  int*   bkt_c2c = (int*)alloc((size_t)ECN * 4);
  int*   bkt_s2c = (int*)alloc((size_t)EEN * 4);
  int*   bkt_c2s = (int*)alloc((size_t)EEN * 4);
  int*   bsum    = (int*)alloc(256 * 4);

  // --- CSR builds ---
  k_hist2z<<<NB2, 256, 0, stream>>>(s2c_dst, blockHist, cnt_c2c);
  k_hist_all<<<(ECN + EEN + 255) / 256, 256, 0, stream>>>(c2c_dst, ECN, cnt_c2c, c2s_dst, EEN, cnt_c2s);
  k_colscan<<<NCC, 64, 0, stream>>>(blockHist, colTotal);
  k_scan2<<<1, 1024, 0, stream>>>(cnt_c2c, off_c2c, colTotal, off_s2c, NCC);
  k_scan_blocks<<<CSBLK, 1024, 0, stream>>>(cnt_c2s, off_c2s, SSN, bsum);
  k_scan_addB<<<CSBLK, 1024, 0, stream>>>(off_c2s, bsum, SSN);
  k_scatter2<<<NB2, 256, 0, stream>>>(s2c_src, s2c_dst, blockHist, off_s2c, bkt_s2c);
  k_scatter_all<<<(ECN + EEN + 255) / 256, 256, 0, stream>>>(
      c2c_src, c2c_dst, off_c2c, cnt2_c2c, bkt_c2c, ECN,
      c2s_src, c2s_dst, off_c2s, cnt2_c2s, bkt_c2s, EEN);

  // --- time-series branch ---
  k_bn<<<TTT, 256, 0, stream>>>(company_ts, bn_gamma, bn_beta, ts_norm);
  k_lstm0<<<(NCC + 3) / 4, 256, 0, stream>>>(ts_norm, Wih0, Whh0, bih0, bhh0, h0seq);
  k_lstm1<<<(NCC + 3) / 4, 256, 0, stream>>>(h0seq, Wih1, Whh1, bih1, bhh1, fc_W, fc_b,
                                             comp_emb, company_ids, comp0);

  // --- sentence projection (MFMA) ---
  k_projm<<<(SSN + 127) / 128, 256, 0, stream>>>(sentence_x, proj_W, proj_b, sent0);

  // --- GIN layer 0 ---
  k_cgin<<<NCC, 1024, 0, stream>>>(comp0, sent0,
                                   off_c2c, bkt_c2c, off_s2c, bkt_s2c,
                                   gin_W + 0 * 4096, gin_b + 0 * 64, gin_a + 0,
                                   gin_W + 1 * 4096, gin_b + 1 * 64, gin_a + 1,
                                   comp1, nullptr, nullptr, nullptr);
  k_sgin<<<SSN / 64, 256, 0, stream>>>(sent0, comp0, off_c2s, bkt_c2s,
                                       gin_W + 2 * 4096, gin_b + 2 * 64, gin_a + 2,
                                       sent0 /* in place */);

  // --- GIN layer 1 (+ fused classifier; new_sent of layer 1 is dead code) ---
  k_cgin<<<NCC, 1024, 0, stream>>>(comp1, sent0,
                                   off_c2c, bkt_c2c, off_s2c, bkt_s2c,
                                   gin_W + 3 * 4096, gin_b + 3 * 64, gin_a + 3,
                                   gin_W + 4 * 4096, gin_b + 4 * 64, gin_a + 4,
                                   nullptr, cls_W, cls_b, outp);
}

// Round 5
// 565.315 us; speedup vs baseline: 2.8165x; 1.2155x over previous
//
#include <hip/hip_runtime.h>

#define NCC 617
#define TTT 15
#define FFF 5
#define SSN 200000
#define EEN 1000000
#define ECN 20000
#define CSBLK 196   /* ceil(SSN/1024) */
#define NB2 512
#define EPB2 ((EEN + NB2 - 1) / NB2)   /* 1954 */
#define ZN (NCC + NCC + SSN + SSN)
#define HALLB ((ECN + EEN + 255) / 256) /* 3985 */

typedef unsigned short u16;
typedef unsigned int   u32;

using short8  = __attribute__((ext_vector_type(8))) short;
using f32x4v  = __attribute__((ext_vector_type(4))) float;

__device__ __forceinline__ float bf2f(u16 u){ return __uint_as_float(((u32)u) << 16); }
__device__ __forceinline__ u16 f2bf(float f){
  u32 x = __float_as_uint(f);
  u32 r = (x + 0x7fffu + ((x >> 16) & 1u)) >> 16;
  return (u16)r;
}
__device__ __forceinline__ u32 pk2(float a, float b){ return (u32)f2bf(a) | ((u32)f2bf(b) << 16); }
__device__ __forceinline__ float sigm(float x){ return 1.0f / (1.0f + __expf(-x)); }

// ---------------- zero counters (must precede histF: atomics need zeroed state) ----------------
__global__ __launch_bounds__(256) void k_zero(int* p, int n){
  int i = blockIdx.x * 256 + threadIdx.x;
  if (i < n) p[i] = 0;
}

// ---------------- fused histograms: s2c LDS block-hist | c2c+c2s global-atomic hist ----------------
__global__ __launch_bounds__(256) void k_histF(const int* __restrict__ s2c_dst, int* __restrict__ blockHist,
                                               const int* __restrict__ c2c_dst, int* __restrict__ cnt_c2c,
                                               const int* __restrict__ c2s_dst, int* __restrict__ cnt_c2s){
  __shared__ int h[NCC];
  int b = blockIdx.x, tid = threadIdx.x;
  if (b < NB2){
    for (int i = tid; i < NCC; i += 256) h[i] = 0;
    __syncthreads();
    int e0 = b * EPB2;
    int e1 = e0 + EPB2; if (e1 > EEN) e1 = EEN;
    for (int e = e0 + tid; e < e1; e += 256) atomicAdd(&h[s2c_dst[e]], 1);
    __syncthreads();
    for (int i = tid; i < NCC; i += 256) blockHist[i * NB2 + b] = h[i];
  } else {
    int i = (b - NB2) * 256 + tid;
    if (i < ECN) atomicAdd(&cnt_c2c[c2c_dst[i]], 1);
    else if (i < ECN + EEN) atomicAdd(&cnt_c2s[c2s_dst[i - ECN]], 1);
  }
}

// ---------------- fused: colscan (617) | c2s block-scan (196) | batchnorm (15) ----------------
__global__ __launch_bounds__(1024) void k_scanA(int* __restrict__ blockHist, int* __restrict__ colTotal,
                                                const int* __restrict__ cnt_c2s, int* __restrict__ off_c2s,
                                                int* __restrict__ bsum,
                                                const float* __restrict__ ts, const float* __restrict__ gamma,
                                                const float* __restrict__ beta, float* __restrict__ tsn){
  __shared__ int buf[1024];
  __shared__ float ss[1024], s2[1024];
  int b = blockIdx.x, tid = threadIdx.x;
  if (b < NCC){
    // per-destination exclusive prefix over NB2 per-block counts (one wave)
    if (tid < 64){
      int lane = tid;
      int base = 0;
      for (int j = 0; j < NB2; j += 64){
        int v = blockHist[b * NB2 + j + lane];
        int orig = v;
        #pragma unroll
        for (int s = 1; s < 64; s <<= 1){
          int t = __shfl_up(v, s, 64);
          if (lane >= s) v += t;
        }
        blockHist[b * NB2 + j + lane] = base + v - orig;
        base += __shfl(v, 63, 64);
      }
      if (lane == 0) colTotal[b] = base;
    }
  } else if (b < NCC + CSBLK) {
    int bb = b - NCC;
    int gi = bb * 1024 + tid;
    int v = (gi < SSN) ? cnt_c2s[gi] : 0;
    buf[tid] = v;
    __syncthreads();
    for (int d = 1; d < 1024; d <<= 1){
      int x = (tid >= d) ? buf[tid - d] : 0;
      __syncthreads();
      buf[tid] += x;
      __syncthreads();
    }
    if (gi < SSN) off_c2s[gi] = buf[tid] - v;   // exclusive within block
    if (tid == 1023) bsum[bb] = buf[1023];
  } else {
    // batchnorm for timestep t
    int t = b - (NCC + CSBLK);
    float a = 0.f, s = 0.f;
    for (int c = tid; c < NCC; c += 1024){
      float v = ts[(c * TTT + t) * FFF + 3];
      a += v; s += v * v;
    }
    ss[tid] = a; s2[tid] = s;
    __syncthreads();
    for (int d = 512; d > 0; d >>= 1){
      if (tid < d){ ss[tid] += ss[tid + d]; s2[tid] += s2[tid + d]; }
      __syncthreads();
    }
    float mean = ss[0] / (float)NCC;
    float var  = s2[0] / (float)NCC - mean * mean;
    float rstd = rsqrtf(var + 1e-5f);
    float g = gamma[t], be = beta[t];
    for (int c = tid; c < NCC; c += 1024){
      float v = ts[(c * TTT + t) * FFF + 3];
      tsn[c * TTT + t] = (v - mean) * rstd * g + be;
    }
  }
}

// ---------------- fused: dual 617-scan (block 0) | c2s scan-add (blocks 1..196) ----------------
__global__ __launch_bounds__(1024) void k_scanB(const int* __restrict__ cnt_c2c, int* __restrict__ off_c2c,
                                                const int* __restrict__ colTotal, int* __restrict__ off_s2c,
                                                int* __restrict__ off_c2s, const int* __restrict__ bsum){
  __shared__ int buf[1024];
  __shared__ int sboff[CSBLK + 1];
  int b = blockIdx.x, tid = threadIdx.x;
  if (b == 0){
    for (int pass = 0; pass < 2; ++pass){
      const int* cnt = pass ? colTotal : cnt_c2c;
      int* ofs = pass ? off_s2c : off_c2c;
      int v = (tid < NCC) ? cnt[tid] : 0;
      buf[tid] = v;
      __syncthreads();
      for (int d = 1; d < 1024; d <<= 1){
        int x = (tid >= d) ? buf[tid - d] : 0;
        __syncthreads();
        buf[tid] += x;
        __syncthreads();
      }
      if (tid < NCC) ofs[tid] = (tid == 0) ? 0 : buf[tid - 1];
      if (tid == 0) ofs[NCC] = buf[NCC - 1];
      __syncthreads();
    }
  } else {
    int bb = b - 1;
    int lane = tid & 63;
    if (tid < 64){
      int base = 0;
      for (int j = 0; j < CSBLK; j += 64){
        int idx = j + lane;
        int v = (idx < CSBLK) ? bsum[idx] : 0;
        int orig = v;
        #pragma unroll
        for (int s = 1; s < 64; s <<= 1){
          int t2 = __shfl_up(v, s, 64);
          if (lane >= s) v += t2;
        }
        if (idx < CSBLK) sboff[idx] = base + v - orig;
        base += __shfl(v, 63, 64);
      }
      if (lane == 0) sboff[CSBLK] = base;
    }
    __syncthreads();
    int gi = bb * 1024 + tid;
    if (gi < SSN) off_c2s[gi] += sboff[bb];
    if (bb == 0 && tid == 0) off_c2s[SSN] = sboff[CSBLK];
  }
}

// ---------------- fused scatter: s2c LDS-cursor | c2c+c2s global-cursor ----------------
__global__ __launch_bounds__(256) void k_scatF(const int* __restrict__ s2c_src, const int* __restrict__ s2c_dst,
                                               const int* __restrict__ blockHist, const int* __restrict__ off_s2c,
                                               int* __restrict__ bkt_s2c,
                                               const int* __restrict__ c2c_src, const int* __restrict__ c2c_dst,
                                               const int* __restrict__ off_c2c, int* __restrict__ cnt2_c2c,
                                               int* __restrict__ bkt_c2c,
                                               const int* __restrict__ c2s_src, const int* __restrict__ c2s_dst,
                                               const int* __restrict__ off_c2s, int* __restrict__ cnt2_c2s,
                                               int* __restrict__ bkt_c2s){
  __shared__ int cur[NCC];
  int b = blockIdx.x, tid = threadIdx.x;
  if (b < NB2){
    for (int i = tid; i < NCC; i += 256) cur[i] = off_s2c[i] + blockHist[i * NB2 + b];
    __syncthreads();
    int e0 = b * EPB2;
    int e1 = e0 + EPB2; if (e1 > EEN) e1 = EEN;
    for (int e = e0 + tid; e < e1; e += 256){
      int d = s2c_dst[e];
      int p = atomicAdd(&cur[d], 1);
      bkt_s2c[p] = s2c_src[e];
    }
  } else {
    int i = (b - NB2) * 256 + tid;
    if (i < ECN){
      int d = c2c_dst[i]; int p = off_c2c[d] + atomicAdd(&cnt2_c2c[d], 1); bkt_c2c[p] = c2c_src[i];
    } else if (i < ECN + EEN){
      int k = i - ECN;
      int d = c2s_dst[k]; int p = off_c2s[d] + atomicAdd(&cnt2_c2s[d], 1); bkt_c2s[p] = c2s_src[k];
    }
  }
}

// ---------------- fused 2-layer LSTM (lockstep per timestep) + fc + emb ----------------
__global__ __launch_bounds__(256, 1) void k_lstm01(const float* __restrict__ tsn,
                                                   const float* __restrict__ Wih0, const float* __restrict__ Whh0,
                                                   const float* __restrict__ bih0, const float* __restrict__ bhh0,
                                                   const float* __restrict__ Wih1, const float* __restrict__ Whh1,
                                                   const float* __restrict__ bih1, const float* __restrict__ bhh1,
                                                   const float* __restrict__ fcW, const float* __restrict__ fcb,
                                                   const float* __restrict__ emb, const int* __restrict__ ids,
                                                   float* __restrict__ comp0){
  __shared__ __align__(16) u16 sW0[64 * 64 * 4];  // 32 KB  [k][j][gate]
  __shared__ __align__(16) u16 sP1[64 * 64 * 8];  // 64 KB  [k][j][ih gates | hh gates]
  __shared__ float sWi[256];
  __shared__ float sB0[256];
  int tid = threadIdx.x;
  for (int i = tid; i < 16384; i += 256){
    int k = i >> 8, j = (i >> 2) & 63, g = i & 3;
    sW0[i] = f2bf(Whh0[(g * 64 + j) * 64 + k]);
  }
  for (int i = tid; i < 32768; i += 256){
    int k = i >> 9, j = (i >> 3) & 63, g = i & 7;
    float v = (g < 4) ? Wih1[(g * 64 + j) * 64 + k] : Whh1[((g - 4) * 64 + j) * 64 + k];
    sP1[i] = f2bf(v);
  }
  sWi[tid] = Wih0[tid];
  sB0[tid] = bih0[tid] + bhh0[tid];
  __syncthreads();
  int wave = tid >> 6, lane = tid & 63;
  int c = blockIdx.x * 4 + wave;
  int ci = (c < NCC) ? c : (NCC - 1);
  float wi_i = sWi[lane], wi_f = sWi[64 + lane], wi_g = sWi[128 + lane], wi_o = sWi[192 + lane];
  float b0i = sB0[lane], b0f = sB0[64 + lane], b0g = sB0[128 + lane], b0o = sB0[192 + lane];
  float b1i = bih1[lane]       + bhh1[lane];
  float b1f = bih1[64 + lane]  + bhh1[64 + lane];
  float b1g = bih1[128 + lane] + bhh1[128 + lane];
  float b1o = bih1[192 + lane] + bhh1[192 + lane];
  float h0 = 0.f, c0 = 0.f, h1 = 0.f, c1 = 0.f;
  for (int t = 0; t < TTT; ++t){
    float x = tsn[ci * TTT + t];
    float gi = b0i + x * wi_i, gf = b0f + x * wi_f, gg = b0g + x * wi_g, go = b0o + x * wi_o;
    #pragma unroll 4
    for (int k = 0; k < 64; ++k){
      float hk = __shfl(h0, k, 64);
      ushort4 w = *(const ushort4*)&sW0[(k * 64 + lane) * 4];
      gi += hk * bf2f(w.x); gf += hk * bf2f(w.y);
      gg += hk * bf2f(w.z); go += hk * bf2f(w.w);
    }
    c0 = sigm(gf) * c0 + sigm(gi) * tanhf(gg);
    h0 = sigm(go) * tanhf(c0);
    gi = b1i; gf = b1f; gg = b1g; go = b1o;
    #pragma unroll 4
    for (int k = 0; k < 64; ++k){
      float xk = __shfl(h0, k, 64);
      float hk = __shfl(h1, k, 64);
      short8 wv = *(const short8*)&sP1[(k * 64 + lane) * 8];
      gi += xk * bf2f((u16)wv[0]) + hk * bf2f((u16)wv[4]);
      gf += xk * bf2f((u16)wv[1]) + hk * bf2f((u16)wv[5]);
      gg += xk * bf2f((u16)wv[2]) + hk * bf2f((u16)wv[6]);
      go += xk * bf2f((u16)wv[3]) + hk * bf2f((u16)wv[7]);
    }
    c1 = sigm(gf) * c1 + sigm(gi) * tanhf(gg);
    h1 = sigm(go) * tanhf(c1);
  }
  __syncthreads();
  float* fws = (float*)sW0;   // reuse: fcW^T [k][d], 16 KB
  for (int i = tid; i < 4096; i += 256){
    int d = i >> 6, k = i & 63;
    fws[k * 64 + d] = fcW[i];
  }
  __syncthreads();
  float y = fcb[lane];
  #pragma unroll 4
  for (int k = 0; k < 64; ++k){
    float hk = __shfl(h1, k, 64);
    y += hk * fws[k * 64 + lane];
  }
  y = fmaxf(y, 0.f);
  if (c < NCC) comp0[c * 64 + lane] = y + emb[ids[c] * 64 + lane];
}

// ---------------- proj GEMM via MFMA (unchanged from R3/R4) ----------------
__global__ __launch_bounds__(256) void k_projm(const float* __restrict__ A, const float* __restrict__ W,
                                               const float* __restrict__ pb, u16* __restrict__ sent0){
  __shared__ __align__(16) u16 sA[128 * 64];
  __shared__ __align__(16) u16 sB[64 * 64];
  char* sAb = (char*)sA;
  char* sBb = (char*)sB;
  int tid = threadIdx.x;
  int wave = tid >> 6, lane = tid & 63;
  int l15 = lane & 15, lg = lane >> 4;
  int s0 = blockIdx.x * 128;

  int rA = tid >> 1, hA = tid & 1;
  int sA_row = s0 + rA; if (sA_row >= SSN) sA_row = SSN - 1;
  const float* gA0 = &A[(size_t)sA_row * 768 + hA * 32];
  u32 aw_base = (u32)(rA * 128 + hA * 64);
  u32 aw_swz  = (u32)((rA & 7) << 4);
  int nB = tid >> 2, qB = tid & 3;
  const float* gB0 = &W[(size_t)nB * 768 + qB * 16];
  u32 bw_base = (u32)(nB * 128 + qB * 32);
  u32 bw_swz  = (u32)((nB & 7) << 4);

  int arow = wave * 32 + l15;
  u32 ar_swz = (u32)((arow & 7) << 4);
  u32 ar_base = (u32)(arow * 128 + lg * 16);
  u32 br_swz = (u32)((l15 & 7) << 4);
  u32 br_base = (u32)(l15 * 128 + lg * 16);

  f32x4v acc[2][4] = {};

  for (int kc = 0; kc < 12; ++kc){
    __syncthreads();
    {
      const float* g = gA0 + kc * 64;
      #pragma unroll
      for (int q = 0; q < 4; ++q){
        float4 va = ((const float4*)g)[2 * q];
        float4 vb = ((const float4*)g)[2 * q + 1];
        uint4 w;
        w.x = pk2(va.x, va.y); w.y = pk2(va.z, va.w);
        w.z = pk2(vb.x, vb.y); w.w = pk2(vb.z, vb.w);
        *(uint4*)(sAb + ((aw_base + q * 16) ^ aw_swz)) = w;
      }
    }
    {
      const float* g = gB0 + kc * 64;
      #pragma unroll
      for (int q = 0; q < 2; ++q){
        float4 va = ((const float4*)g)[2 * q];
        float4 vb = ((const float4*)g)[2 * q + 1];
        uint4 w;
        w.x = pk2(va.x, va.y); w.y = pk2(va.z, va.w);
        w.z = pk2(vb.x, vb.y); w.w = pk2(vb.z, vb.w);
        *(uint4*)(sBb + ((bw_base + q * 16) ^ bw_swz)) = w;
      }
    }
    __syncthreads();
    #pragma unroll
    for (int ks = 0; ks < 2; ++ks){
      short8 a0 = *(const short8*)(sAb + ((ar_base + 0    + ks * 64) ^ ar_swz));
      short8 a1 = *(const short8*)(sAb + ((ar_base + 2048 + ks * 64) ^ ar_swz));
      short8 b0 = *(const short8*)(sBb + ((br_base + 0    + ks * 64) ^ br_swz));
      short8 b1 = *(const short8*)(sBb + ((br_base + 2048 + ks * 64) ^ br_swz));
      short8 b2 = *(const short8*)(sBb + ((br_base + 4096 + ks * 64) ^ br_swz));
      short8 b3 = *(const short8*)(sBb + ((br_base + 6144 + ks * 64) ^ br_swz));
      acc[0][0] = __builtin_amdgcn_mfma_f32_16x16x32_bf16(a0, b0, acc[0][0], 0, 0, 0);
      acc[0][1] = __builtin_amdgcn_mfma_f32_16x16x32_bf16(a0, b1, acc[0][1], 0, 0, 0);
      acc[0][2] = __builtin_amdgcn_mfma_f32_16x16x32_bf16(a0, b2, acc[0][2], 0, 0, 0);
      acc[0][3] = __builtin_amdgcn_mfma_f32_16x16x32_bf16(a0, b3, acc[0][3], 0, 0, 0);
      acc[1][0] = __builtin_amdgcn_mfma_f32_16x16x32_bf16(a1, b0, acc[1][0], 0, 0, 0);
      acc[1][1] = __builtin_amdgcn_mfma_f32_16x16x32_bf16(a1, b1, acc[1][1], 0, 0, 0);
      acc[1][2] = __builtin_amdgcn_mfma_f32_16x16x32_bf16(a1, b2, acc[1][2], 0, 0, 0);
      acc[1][3] = __builtin_amdgcn_mfma_f32_16x16x32_bf16(a1, b3, acc[1][3], 0, 0, 0);
    }
  }

  float bias[4];
  #pragma unroll
  for (int nt = 0; nt < 4; ++nt) bias[nt] = pb[nt * 16 + l15];
  #pragma unroll
  for (int mt = 0; mt < 2; ++mt){
    #pragma unroll
    for (int j = 0; j < 4; ++j){
      int s = s0 + wave * 32 + mt * 16 + lg * 4 + j;
      if (s < SSN){
        #pragma unroll
        for (int nt = 0; nt < 4; ++nt)
          sent0[(size_t)s * 64 + nt * 16 + l15] = f2bf(acc[mt][nt][j] + bias[nt]);
      }
    }
  }
}

// ---------------- sentence GIN via MFMA (in-place) ----------------
__global__ __launch_bounds__(256) void k_sgin(const u16* __restrict__ sentIn, const float* __restrict__ compIn,
                                              const int* __restrict__ ofs, const int* __restrict__ bkt,
                                              const float* __restrict__ W, const float* __restrict__ b,
                                              const float* __restrict__ aP, u16* __restrict__ sentOut){
  __shared__ __align__(16) u16 sX[64 * 64];   // [s][k] bf16, byte ^= (s&7)<<4
  __shared__ __align__(16) u16 sW[64 * 64];   // [n][k] bf16, same swizzle
  __shared__ int eb[512];
  __shared__ int sofs[65];
  char* sXb = (char*)sX;
  char* sWb = (char*)sW;
  int tid = threadIdx.x;
  // stage W (16 floats per thread)
  {
    int n = tid >> 2, q = tid & 3;
    const float* g = &W[n * 64 + q * 16];
    u32 wbase = (u32)(n * 128 + q * 32);
    u32 wswz  = (u32)((n & 7) << 4);
    #pragma unroll
    for (int hh = 0; hh < 2; ++hh){
      float4 va = ((const float4*)g)[2 * hh];
      float4 vb = ((const float4*)g)[2 * hh + 1];
      uint4 w;
      w.x = pk2(va.x, va.y); w.y = pk2(va.z, va.w);
      w.z = pk2(vb.x, vb.y); w.w = pk2(vb.z, vb.w);
      *(uint4*)(sWb + ((wbase + hh * 16) ^ wswz)) = w;
    }
  }
  int sBase = blockIdx.x * 64;
  if (tid < 65) sofs[tid] = ofs[sBase + tid];
  __syncthreads();
  int E0 = sofs[0];
  int tot = sofs[64] - E0;
  int staged = tot < 512 ? tot : 512;
  for (int i = tid; i < staged; i += 256) eb[i] = bkt[E0 + i];
  __syncthreads();
  int wave = tid >> 6, lane = tid & 63;
  for (int q = 0; q < 16; ++q){
    int sL = wave * 16 + q;
    int s = sBase + sL;
    float acc = bf2f(sentIn[(size_t)s * 64 + lane]);
    int e0 = sofs[sL], e1 = sofs[sL + 1];
    for (int e = e0; e < e1; ++e){
      int r = e - E0;
      int src = (r < 512) ? eb[r] : bkt[e];
      acc += compIn[src * 64 + lane];
    }
    *(u16*)(sXb + (((u32)(sL * 128 + lane * 2)) ^ ((u32)((sL & 7) << 4)))) = f2bf(acc);
  }
  __syncthreads();
  // MFMA: wave owns rows [16*wave, 16*wave+16)
  int l15 = lane & 15, lg = lane >> 4;
  int arow = wave * 16 + l15;
  u32 ar_swz = (u32)((arow & 7) << 4);
  u32 br_swz = (u32)((l15 & 7) << 4);   // (nt*16+l15)&7 == l15&7
  f32x4v acc4[4] = {};
  #pragma unroll
  for (int ks = 0; ks < 2; ++ks){
    short8 a0 = *(const short8*)(sXb + (((u32)(arow * 128 + ks * 64 + lg * 16)) ^ ar_swz));
    #pragma unroll
    for (int nt = 0; nt < 4; ++nt){
      short8 b0 = *(const short8*)(sWb + (((u32)((nt * 16 + l15) * 128 + ks * 64 + lg * 16)) ^ br_swz));
      acc4[nt] = __builtin_amdgcn_mfma_f32_16x16x32_bf16(a0, b0, acc4[nt], 0, 0, 0);
    }
  }
  float alpha = *aP;
  #pragma unroll
  for (int nt = 0; nt < 4; ++nt){
    float bb = b[nt * 16 + l15];
    #pragma unroll
    for (int j = 0; j < 4; ++j){
      int srow = sBase + wave * 16 + lg * 4 + j;
      float h = acc4[nt][j] + bb;
      h = (h >= 0.f) ? h : alpha * h;
      sentOut[(size_t)srow * 64 + nt * 16 + l15] = f2bf(h);
    }
  }
}

// ---------------- company GIN, LDS-staged edge indices; optional fused classifier ----------------
__global__ __launch_bounds__(1024) void k_cgin(const float* __restrict__ compIn, const u16* __restrict__ sentIn,
                                               const int* __restrict__ ofsA, const int* __restrict__ bktA,
                                               const int* __restrict__ ofsB, const int* __restrict__ bktB,
                                               const float* __restrict__ Wa, const float* __restrict__ ba, const float* aaP,
                                               const float* __restrict__ Wb, const float* __restrict__ bb, const float* abP,
                                               float* __restrict__ compOut,
                                               const float* __restrict__ clsW, const float* __restrict__ clsb,
                                               float* __restrict__ outp){
  __shared__ __align__(16) float Wat[64 * 68];
  __shared__ __align__(16) float Wbt[64 * 68];
  __shared__ int eidx[2048];
  __shared__ float part[16][2][64];
  __shared__ float xa[64], xb[64], outab[128];
  int tid = threadIdx.x;
  for (int i = tid; i < 4096; i += 1024){
    int j = i >> 6, k = i & 63;
    Wat[k * 68 + j] = Wa[i];
    Wbt[k * 68 + j] = Wb[i];
  }
  int wave = tid >> 6, lane = tid & 63;
  int c = blockIdx.x;
  float accA = 0.f, accB = 0.f;
  int a0 = ofsA[c], a1 = ofsA[c + 1];
  for (int base = a0; base < a1; base += 2048){
    int cnt = a1 - base; if (cnt > 2048) cnt = 2048;
    __syncthreads();
    for (int i = tid; i < cnt; i += 1024) eidx[i] = bktA[base + i];
    __syncthreads();
    for (int i = wave; i < cnt; i += 16) accA += compIn[eidx[i] * 64 + lane];
  }
  int b0 = ofsB[c], b1 = ofsB[c + 1];
  for (int base = b0; base < b1; base += 2048){
    int cnt = b1 - base; if (cnt > 2048) cnt = 2048;
    __syncthreads();
    for (int i = tid; i < cnt; i += 1024) eidx[i] = bktB[base + i];
    __syncthreads();
    #pragma unroll 4
    for (int i = wave; i < cnt; i += 16) accB += bf2f(sentIn[(size_t)eidx[i] * 64 + lane]);
  }
  part[wave][0][lane] = accA;
  part[wave][1][lane] = accB;
  __syncthreads();
  if (tid < 128){
    int l = tid & 63, which = tid >> 6;
    float m = 0.f;
    #pragma unroll
    for (int w = 0; w < 16; ++w) m += part[w][which][l];
    float ci = compIn[c * 64 + l];
    if (which == 0) xa[l] = ci + m; else xb[l] = ci + m;
  }
  __syncthreads();
  if (tid < 128){
    int j = tid & 63;
    const float* X  = (tid < 64) ? xa : xb;
    const float* Wt = (tid < 64) ? Wat : Wbt;
    float acc = (tid < 64) ? ba[j] : bb[j];
    #pragma unroll 4
    for (int k = 0; k < 64; ++k) acc += X[k] * Wt[k * 68 + j];
    float al = (tid < 64) ? *aaP : *abP;
    outab[tid] = (acc >= 0.f) ? acc : al * acc;
  }
  __syncthreads();
  if (clsW){
    if (tid < 64) xa[tid] = outab[tid] + outab[64 + tid];
    __syncthreads();
    if (tid < 128){
      int j = tid >> 6;
      float p = xa[lane] * clsW[j * 64 + lane];
      #pragma unroll
      for (int s = 32; s > 0; s >>= 1) p += __shfl_down(p, s, 64);
      if (lane == 0) outp[c * 2 + j] = p + clsb[j];
    }
  } else {
    if (tid < 64) compOut[c * 64 + tid] = outab[tid] + outab[64 + tid];
  }
}

extern "C" void kernel_launch(void* const* d_in, const int* in_sizes, int n_in,
                              void* d_out, int out_size, void* d_ws, size_t ws_size,
                              hipStream_t stream) {
  (void)in_sizes; (void)n_in; (void)out_size; (void)ws_size;
  const float* company_ts = (const float*)d_in[0];
  const float* sentence_x = (const float*)d_in[1];
  const int*   company_ids = (const int*)d_in[2];
  const int*   c2c_src = (const int*)d_in[3];
  const int*   c2c_dst = (const int*)d_in[4];
  const int*   s2c_src = (const int*)d_in[5];
  const int*   s2c_dst = (const int*)d_in[6];
  const int*   c2s_src = (const int*)d_in[7];
  const int*   c2s_dst = (const int*)d_in[8];
  const float* bn_gamma = (const float*)d_in[9];
  const float* bn_beta  = (const float*)d_in[10];
  const float* Wih0 = (const float*)d_in[11];
  const float* Whh0 = (const float*)d_in[12];
  const float* bih0 = (const float*)d_in[13];
  const float* bhh0 = (const float*)d_in[14];
  const float* Wih1 = (const float*)d_in[15];
  const float* Whh1 = (const float*)d_in[16];
  const float* bih1 = (const float*)d_in[17];
  const float* bhh1 = (const float*)d_in[18];
  const float* fc_W = (const float*)d_in[19];
  const float* fc_b = (const float*)d_in[20];
  const float* comp_emb = (const float*)d_in[21];
  const float* proj_W = (const float*)d_in[22];
  const float* proj_b = (const float*)d_in[23];
  const float* gin_W = (const float*)d_in[24];
  const float* gin_b = (const float*)d_in[25];
  const float* gin_a = (const float*)d_in[26];
  const float* cls_W = (const float*)d_in[27];
  const float* cls_b = (const float*)d_in[28];
  float* outp = (float*)d_out;

  char* ws = (char*)d_ws;
  size_t off = 0;
  auto alloc = [&](size_t bytes)->char* {
    char* r = ws + off;
    off += (bytes + 255) & ~(size_t)255;
    return r;
  };
  float* ts_norm = (float*)alloc((size_t)NCC * TTT * 4);
  float* comp0   = (float*)alloc((size_t)NCC * 64 * 4);
  float* comp1   = (float*)alloc((size_t)NCC * 64 * 4);
  u16*   sent0   = (u16*)alloc((size_t)SSN * 64 * 2);   // reused in place as sent1
  int*   blockHist = (int*)alloc((size_t)NCC * NB2 * 4);
  int*   colTotal  = (int*)alloc((size_t)NCC * 4);
  int*   cnt_c2c  = (int*)alloc((size_t)ZN * 4);
  int*   cnt2_c2c = cnt_c2c + NCC;
  int*   cnt_c2s  = cnt2_c2c + NCC;
  int*   cnt2_c2s = cnt_c2s + SSN;
  int*   off_c2c = (int*)alloc((size_t)(NCC + 1) * 4);
  int*   off_s2c = (int*)alloc((size_t)(NCC + 1) * 4);
  int*   off_c2s = (int*)alloc((size_t)(SSN + 1) * 4);
  int*   bkt_c2c = (int*)alloc((size_t)ECN * 4);
  int*   bkt_s2c = (int*)alloc((size_t)EEN * 4);
  int*   bkt_c2s = (int*)alloc((size_t)EEN * 4);
  int*   bsum    = (int*)alloc(256 * 4);

  // --- CSR builds + bn (fused) ---
  k_zero<<<(ZN + 255) / 256, 256, 0, stream>>>(cnt_c2c, ZN);
  k_histF<<<NB2 + HALLB, 256, 0, stream>>>(s2c_dst, blockHist, c2c_dst, cnt_c2c, c2s_dst, cnt_c2s);
  k_scanA<<<NCC + CSBLK + TTT, 1024, 0, stream>>>(blockHist, colTotal, cnt_c2s, off_c2s, bsum,
                                                  company_ts, bn_gamma, bn_beta, ts_norm);
  k_scanB<<<1 + CSBLK, 1024, 0, stream>>>(cnt_c2c, off_c2c, colTotal, off_s2c, off_c2s, bsum);
  k_scatF<<<NB2 + HALLB, 256, 0, stream>>>(s2c_src, s2c_dst, blockHist, off_s2c, bkt_s2c,
                                           c2c_src, c2c_dst, off_c2c, cnt2_c2c, bkt_c2c,
                                           c2s_src, c2s_dst, off_c2s, cnt2_c2s, bkt_c2s);

  // --- time-series branch (fused 2-layer LSTM) ---
  k_lstm01<<<(NCC + 3) / 4, 256, 0, stream>>>(ts_norm, Wih0, Whh0, bih0, bhh0,
                                              Wih1, Whh1, bih1, bhh1,
                                              fc_W, fc_b, comp_emb, company_ids, comp0);

  // --- sentence projection (MFMA) ---
  k_projm<<<(SSN + 127) / 128, 256, 0, stream>>>(sentence_x, proj_W, proj_b, sent0);

  // --- GIN layer 0 ---
  k_cgin<<<NCC, 1024, 0, stream>>>(comp0, sent0,
                                   off_c2c, bkt_c2c, off_s2c, bkt_s2c,
                                   gin_W + 0 * 4096, gin_b + 0 * 64, gin_a + 0,
                                   gin_W + 1 * 4096, gin_b + 1 * 64, gin_a + 1,
                                   comp1, nullptr, nullptr, nullptr);
  k_sgin<<<SSN / 64, 256, 0, stream>>>(sent0, comp0, off_c2s, bkt_c2s,
                                       gin_W + 2 * 4096, gin_b + 2 * 64, gin_a + 2,
                                       sent0 /* in place */);

  // --- GIN layer 1 (+ fused classifier; layer-1 new_sent is dead code) ---
  k_cgin<<<NCC, 1024, 0, stream>>>(comp1, sent0,
                                   off_c2c, bkt_c2c, off_s2c, bkt_s2c,
                                   gin_W + 3 * 4096, gin_b + 3 * 64, gin_a + 3,
                                   gin_W + 4 * 4096, gin_b + 4 * 64, gin_a + 4,
                                   nullptr, cls_W, cls_b, outp);
}

// Round 6
// 552.255 us; speedup vs baseline: 2.8831x; 1.0236x over previous
//
#include <hip/hip_runtime.h>

#define NCC 617
#define TTT 15
#define FFF 5
#define SSN 200000
#define EEN 1000000
#define ECN 20000
#define CSBLK 196   /* ceil(SSN/1024) */
#define NB2 512
#define EPB2 ((EEN + NB2 - 1) / NB2)   /* 1954 */
#define ZN (NCC + NCC + SSN + SSN)
#define HALLB ((ECN + EEN + 255) / 256) /* 3985 */
#define SGB 782     /* ceil(SSN/256) sentence-gin blocks */

typedef unsigned short u16;
typedef unsigned int   u32;

using short8  = __attribute__((ext_vector_type(8))) short;
using f32x4v  = __attribute__((ext_vector_type(4))) float;

__device__ __forceinline__ float bf2f(u16 u){ return __uint_as_float(((u32)u) << 16); }
__device__ __forceinline__ u16 f2bf(float f){
  u32 x = __float_as_uint(f);
  u32 r = (x + 0x7fffu + ((x >> 16) & 1u)) >> 16;
  return (u16)r;
}
__device__ __forceinline__ u32 pk2(float a, float b){ return (u32)f2bf(a) | ((u32)f2bf(b) << 16); }
__device__ __forceinline__ float sigm(float x){ return 1.0f / (1.0f + __expf(-x)); }

// ---------------- zero counters ----------------
__global__ __launch_bounds__(256) void k_zero(int* p, int n){
  int i = blockIdx.x * 256 + threadIdx.x;
  if (i < n) p[i] = 0;
}

// ---------------- fused histograms: s2c LDS block-hist | c2c+c2s global-atomic hist ----------------
__global__ __launch_bounds__(256) void k_histF(const int* __restrict__ s2c_dst, int* __restrict__ blockHist,
                                               const int* __restrict__ c2c_dst, int* __restrict__ cnt_c2c,
                                               const int* __restrict__ c2s_dst, int* __restrict__ cnt_c2s){
  __shared__ int h[NCC];
  int b = blockIdx.x, tid = threadIdx.x;
  if (b < NB2){
    for (int i = tid; i < NCC; i += 256) h[i] = 0;
    __syncthreads();
    int e0 = b * EPB2;
    int e1 = e0 + EPB2; if (e1 > EEN) e1 = EEN;
    for (int e = e0 + tid; e < e1; e += 256) atomicAdd(&h[s2c_dst[e]], 1);
    __syncthreads();
    for (int i = tid; i < NCC; i += 256) blockHist[i * NB2 + b] = h[i];
  } else {
    int i = (b - NB2) * 256 + tid;
    if (i < ECN) atomicAdd(&cnt_c2c[c2c_dst[i]], 1);
    else if (i < ECN + EEN) atomicAdd(&cnt_c2s[c2s_dst[i - ECN]], 1);
  }
}

// ---------------- fused: colscan (617) | c2s block-scan (196) | batchnorm (15) ----------------
__global__ __launch_bounds__(1024) void k_scanA(int* __restrict__ blockHist, int* __restrict__ colTotal,
                                                const int* __restrict__ cnt_c2s, int* __restrict__ off_c2s,
                                                int* __restrict__ bsum,
                                                const float* __restrict__ ts, const float* __restrict__ gamma,
                                                const float* __restrict__ beta, float* __restrict__ tsn){
  __shared__ int buf[1024];
  __shared__ float ss[1024], s2[1024];
  int b = blockIdx.x, tid = threadIdx.x;
  if (b < NCC){
    if (tid < 64){
      int lane = tid;
      int base = 0;
      for (int j = 0; j < NB2; j += 64){
        int v = blockHist[b * NB2 + j + lane];
        int orig = v;
        #pragma unroll
        for (int s = 1; s < 64; s <<= 1){
          int t = __shfl_up(v, s, 64);
          if (lane >= s) v += t;
        }
        blockHist[b * NB2 + j + lane] = base + v - orig;
        base += __shfl(v, 63, 64);
      }
      if (lane == 0) colTotal[b] = base;
    }
  } else if (b < NCC + CSBLK) {
    int bb = b - NCC;
    int gi = bb * 1024 + tid;
    int v = (gi < SSN) ? cnt_c2s[gi] : 0;
    buf[tid] = v;
    __syncthreads();
    for (int d = 1; d < 1024; d <<= 1){
      int x = (tid >= d) ? buf[tid - d] : 0;
      __syncthreads();
      buf[tid] += x;
      __syncthreads();
    }
    if (gi < SSN) off_c2s[gi] = buf[tid] - v;
    if (tid == 1023) bsum[bb] = buf[1023];
  } else {
    int t = b - (NCC + CSBLK);
    float a = 0.f, s = 0.f;
    for (int c = tid; c < NCC; c += 1024){
      float v = ts[(c * TTT + t) * FFF + 3];
      a += v; s += v * v;
    }
    ss[tid] = a; s2[tid] = s;
    __syncthreads();
    for (int d = 512; d > 0; d >>= 1){
      if (tid < d){ ss[tid] += ss[tid + d]; s2[tid] += s2[tid + d]; }
      __syncthreads();
    }
    float mean = ss[0] / (float)NCC;
    float var  = s2[0] / (float)NCC - mean * mean;
    float rstd = rsqrtf(var + 1e-5f);
    float g = gamma[t], be = beta[t];
    for (int c = tid; c < NCC; c += 1024){
      float v = ts[(c * TTT + t) * FFF + 3];
      tsn[c * TTT + t] = (v - mean) * rstd * g + be;
    }
  }
}

// ---------------- fused: dual 617-scan (block 0) | c2s scan-add (blocks 1..196) ----------------
__global__ __launch_bounds__(1024) void k_scanB(const int* __restrict__ cnt_c2c, int* __restrict__ off_c2c,
                                                const int* __restrict__ colTotal, int* __restrict__ off_s2c,
                                                int* __restrict__ off_c2s, const int* __restrict__ bsum){
  __shared__ int buf[1024];
  __shared__ int sboff[CSBLK + 1];
  int b = blockIdx.x, tid = threadIdx.x;
  if (b == 0){
    for (int pass = 0; pass < 2; ++pass){
      const int* cnt = pass ? colTotal : cnt_c2c;
      int* ofs = pass ? off_s2c : off_c2c;
      int v = (tid < NCC) ? cnt[tid] : 0;
      buf[tid] = v;
      __syncthreads();
      for (int d = 1; d < 1024; d <<= 1){
        int x = (tid >= d) ? buf[tid - d] : 0;
        __syncthreads();
        buf[tid] += x;
        __syncthreads();
      }
      if (tid < NCC) ofs[tid] = (tid == 0) ? 0 : buf[tid - 1];
      if (tid == 0) ofs[NCC] = buf[NCC - 1];
      __syncthreads();
    }
  } else {
    int bb = b - 1;
    int lane = tid & 63;
    if (tid < 64){
      int base = 0;
      for (int j = 0; j < CSBLK; j += 64){
        int idx = j + lane;
        int v = (idx < CSBLK) ? bsum[idx] : 0;
        int orig = v;
        #pragma unroll
        for (int s = 1; s < 64; s <<= 1){
          int t2 = __shfl_up(v, s, 64);
          if (lane >= s) v += t2;
        }
        if (idx < CSBLK) sboff[idx] = base + v - orig;
        base += __shfl(v, 63, 64);
      }
      if (lane == 0) sboff[CSBLK] = base;
    }
    __syncthreads();
    int gi = bb * 1024 + tid;
    if (gi < SSN) off_c2s[gi] += sboff[bb];
    if (bb == 0 && tid == 0) off_c2s[SSN] = sboff[CSBLK];
  }
}

// ---------------- fused scatter ----------------
__global__ __launch_bounds__(256) void k_scatF(const int* __restrict__ s2c_src, const int* __restrict__ s2c_dst,
                                               const int* __restrict__ blockHist, const int* __restrict__ off_s2c,
                                               int* __restrict__ bkt_s2c,
                                               const int* __restrict__ c2c_src, const int* __restrict__ c2c_dst,
                                               const int* __restrict__ off_c2c, int* __restrict__ cnt2_c2c,
                                               int* __restrict__ bkt_c2c,
                                               const int* __restrict__ c2s_src, const int* __restrict__ c2s_dst,
                                               const int* __restrict__ off_c2s, int* __restrict__ cnt2_c2s,
                                               int* __restrict__ bkt_c2s){
  __shared__ int cur[NCC];
  int b = blockIdx.x, tid = threadIdx.x;
  if (b < NB2){
    for (int i = tid; i < NCC; i += 256) cur[i] = off_s2c[i] + blockHist[i * NB2 + b];
    __syncthreads();
    int e0 = b * EPB2;
    int e1 = e0 + EPB2; if (e1 > EEN) e1 = EEN;
    for (int e = e0 + tid; e < e1; e += 256){
      int d = s2c_dst[e];
      int p = atomicAdd(&cur[d], 1);
      bkt_s2c[p] = s2c_src[e];
    }
  } else {
    int i = (b - NB2) * 256 + tid;
    if (i < ECN){
      int d = c2c_dst[i]; int p = off_c2c[d] + atomicAdd(&cnt2_c2c[d], 1); bkt_c2c[p] = c2c_src[i];
    } else if (i < ECN + EEN){
      int k = i - ECN;
      int d = c2s_dst[k]; int p = off_c2s[d] + atomicAdd(&cnt2_c2s[d], 1); bkt_c2s[p] = c2s_src[k];
    }
  }
}

// ---------------- fused 2-layer LSTM + fc + emb ----------------
__global__ __launch_bounds__(256, 1) void k_lstm01(const float* __restrict__ tsn,
                                                   const float* __restrict__ Wih0, const float* __restrict__ Whh0,
                                                   const float* __restrict__ bih0, const float* __restrict__ bhh0,
                                                   const float* __restrict__ Wih1, const float* __restrict__ Whh1,
                                                   const float* __restrict__ bih1, const float* __restrict__ bhh1,
                                                   const float* __restrict__ fcW, const float* __restrict__ fcb,
                                                   const float* __restrict__ emb, const int* __restrict__ ids,
                                                   float* __restrict__ comp0){
  __shared__ __align__(16) u16 sW0[64 * 64 * 4];
  __shared__ __align__(16) u16 sP1[64 * 64 * 8];
  __shared__ float sWi[256];
  __shared__ float sB0[256];
  int tid = threadIdx.x;
  for (int i = tid; i < 16384; i += 256){
    int k = i >> 8, j = (i >> 2) & 63, g = i & 3;
    sW0[i] = f2bf(Whh0[(g * 64 + j) * 64 + k]);
  }
  for (int i = tid; i < 32768; i += 256){
    int k = i >> 9, j = (i >> 3) & 63, g = i & 7;
    float v = (g < 4) ? Wih1[(g * 64 + j) * 64 + k] : Whh1[((g - 4) * 64 + j) * 64 + k];
    sP1[i] = f2bf(v);
  }
  sWi[tid] = Wih0[tid];
  sB0[tid] = bih0[tid] + bhh0[tid];
  __syncthreads();
  int wave = tid >> 6, lane = tid & 63;
  int c = blockIdx.x * 4 + wave;
  int ci = (c < NCC) ? c : (NCC - 1);
  float wi_i = sWi[lane], wi_f = sWi[64 + lane], wi_g = sWi[128 + lane], wi_o = sWi[192 + lane];
  float b0i = sB0[lane], b0f = sB0[64 + lane], b0g = sB0[128 + lane], b0o = sB0[192 + lane];
  float b1i = bih1[lane]       + bhh1[lane];
  float b1f = bih1[64 + lane]  + bhh1[64 + lane];
  float b1g = bih1[128 + lane] + bhh1[128 + lane];
  float b1o = bih1[192 + lane] + bhh1[192 + lane];
  float h0 = 0.f, c0 = 0.f, h1 = 0.f, c1 = 0.f;
  for (int t = 0; t < TTT; ++t){
    float x = tsn[ci * TTT + t];
    float gi = b0i + x * wi_i, gf = b0f + x * wi_f, gg = b0g + x * wi_g, go = b0o + x * wi_o;
    #pragma unroll 4
    for (int k = 0; k < 64; ++k){
      float hk = __shfl(h0, k, 64);
      ushort4 w = *(const ushort4*)&sW0[(k * 64 + lane) * 4];
      gi += hk * bf2f(w.x); gf += hk * bf2f(w.y);
      gg += hk * bf2f(w.z); go += hk * bf2f(w.w);
    }
    c0 = sigm(gf) * c0 + sigm(gi) * tanhf(gg);
    h0 = sigm(go) * tanhf(c0);
    gi = b1i; gf = b1f; gg = b1g; go = b1o;
    #pragma unroll 4
    for (int k = 0; k < 64; ++k){
      float xk = __shfl(h0, k, 64);
      float hk = __shfl(h1, k, 64);
      short8 wv = *(const short8*)&sP1[(k * 64 + lane) * 8];
      gi += xk * bf2f((u16)wv[0]) + hk * bf2f((u16)wv[4]);
      gf += xk * bf2f((u16)wv[1]) + hk * bf2f((u16)wv[5]);
      gg += xk * bf2f((u16)wv[2]) + hk * bf2f((u16)wv[6]);
      go += xk * bf2f((u16)wv[3]) + hk * bf2f((u16)wv[7]);
    }
    c1 = sigm(gf) * c1 + sigm(gi) * tanhf(gg);
    h1 = sigm(go) * tanhf(c1);
  }
  __syncthreads();
  float* fws = (float*)sW0;
  for (int i = tid; i < 4096; i += 256){
    int d = i >> 6, k = i & 63;
    fws[k * 64 + d] = fcW[i];
  }
  __syncthreads();
  float y = fcb[lane];
  #pragma unroll 4
  for (int k = 0; k < 64; ++k){
    float hk = __shfl(h1, k, 64);
    y += hk * fws[k * 64 + lane];
  }
  y = fmaxf(y, 0.f);
  if (c < NCC) comp0[c * 64 + lane] = y + emb[ids[c] * 64 + lane];
}

// ---------------- proj GEMM via MFMA ----------------
__global__ __launch_bounds__(256) void k_projm(const float* __restrict__ A, const float* __restrict__ W,
                                               const float* __restrict__ pb, u16* __restrict__ sent0){
  __shared__ __align__(16) u16 sA[128 * 64];
  __shared__ __align__(16) u16 sB[64 * 64];
  char* sAb = (char*)sA;
  char* sBb = (char*)sB;
  int tid = threadIdx.x;
  int wave = tid >> 6, lane = tid & 63;
  int l15 = lane & 15, lg = lane >> 4;
  int s0 = blockIdx.x * 128;

  int rA = tid >> 1, hA = tid & 1;
  int sA_row = s0 + rA; if (sA_row >= SSN) sA_row = SSN - 1;
  const float* gA0 = &A[(size_t)sA_row * 768 + hA * 32];
  u32 aw_base = (u32)(rA * 128 + hA * 64);
  u32 aw_swz  = (u32)((rA & 7) << 4);
  int nB = tid >> 2, qB = tid & 3;
  const float* gB0 = &W[(size_t)nB * 768 + qB * 16];
  u32 bw_base = (u32)(nB * 128 + qB * 32);
  u32 bw_swz  = (u32)((nB & 7) << 4);

  int arow = wave * 32 + l15;
  u32 ar_swz = (u32)((arow & 7) << 4);
  u32 ar_base = (u32)(arow * 128 + lg * 16);
  u32 br_swz = (u32)((l15 & 7) << 4);
  u32 br_base = (u32)(l15 * 128 + lg * 16);

  f32x4v acc[2][4] = {};

  for (int kc = 0; kc < 12; ++kc){
    __syncthreads();
    {
      const float* g = gA0 + kc * 64;
      #pragma unroll
      for (int q = 0; q < 4; ++q){
        float4 va = ((const float4*)g)[2 * q];
        float4 vb = ((const float4*)g)[2 * q + 1];
        uint4 w;
        w.x = pk2(va.x, va.y); w.y = pk2(va.z, va.w);
        w.z = pk2(vb.x, vb.y); w.w = pk2(vb.z, vb.w);
        *(uint4*)(sAb + ((aw_base + q * 16) ^ aw_swz)) = w;
      }
    }
    {
      const float* g = gB0 + kc * 64;
      #pragma unroll
      for (int q = 0; q < 2; ++q){
        float4 va = ((const float4*)g)[2 * q];
        float4 vb = ((const float4*)g)[2 * q + 1];
        uint4 w;
        w.x = pk2(va.x, va.y); w.y = pk2(va.z, va.w);
        w.z = pk2(vb.x, vb.y); w.w = pk2(vb.z, vb.w);
        *(uint4*)(sBb + ((bw_base + q * 16) ^ bw_swz)) = w;
      }
    }
    __syncthreads();
    #pragma unroll
    for (int ks = 0; ks < 2; ++ks){
      short8 a0 = *(const short8*)(sAb + ((ar_base + 0    + ks * 64) ^ ar_swz));
      short8 a1 = *(const short8*)(sAb + ((ar_base + 2048 + ks * 64) ^ ar_swz));
      short8 b0 = *(const short8*)(sBb + ((br_base + 0    + ks * 64) ^ br_swz));
      short8 b1 = *(const short8*)(sBb + ((br_base + 2048 + ks * 64) ^ br_swz));
      short8 b2 = *(const short8*)(sBb + ((br_base + 4096 + ks * 64) ^ br_swz));
      short8 b3 = *(const short8*)(sBb + ((br_base + 6144 + ks * 64) ^ br_swz));
      acc[0][0] = __builtin_amdgcn_mfma_f32_16x16x32_bf16(a0, b0, acc[0][0], 0, 0, 0);
      acc[0][1] = __builtin_amdgcn_mfma_f32_16x16x32_bf16(a0, b1, acc[0][1], 0, 0, 0);
      acc[0][2] = __builtin_amdgcn_mfma_f32_16x16x32_bf16(a0, b2, acc[0][2], 0, 0, 0);
      acc[0][3] = __builtin_amdgcn_mfma_f32_16x16x32_bf16(a0, b3, acc[0][3], 0, 0, 0);
      acc[1][0] = __builtin_amdgcn_mfma_f32_16x16x32_bf16(a1, b0, acc[1][0], 0, 0, 0);
      acc[1][1] = __builtin_amdgcn_mfma_f32_16x16x32_bf16(a1, b1, acc[1][1], 0, 0, 0);
      acc[1][2] = __builtin_amdgcn_mfma_f32_16x16x32_bf16(a1, b2, acc[1][2], 0, 0, 0);
      acc[1][3] = __builtin_amdgcn_mfma_f32_16x16x32_bf16(a1, b3, acc[1][3], 0, 0, 0);
    }
  }

  float bias[4];
  #pragma unroll
  for (int nt = 0; nt < 4; ++nt) bias[nt] = pb[nt * 16 + l15];
  #pragma unroll
  for (int mt = 0; mt < 2; ++mt){
    #pragma unroll
    for (int j = 0; j < 4; ++j){
      int s = s0 + wave * 32 + mt * 16 + lg * 4 + j;
      if (s < SSN){
        #pragma unroll
        for (int nt = 0; nt < 4; ++nt)
          sent0[(size_t)s * 64 + nt * 16 + l15] = f2bf(acc[mt][nt][j] + bias[nt]);
      }
    }
  }
}

// ---------------- merged GIN layer 0: blocks [0,NCC) = company-GIN, [NCC, NCC+SGB) = sentence-GIN ----------------
__global__ __launch_bounds__(1024) void k_gin0(const float* __restrict__ compIn, const u16* __restrict__ sentIn,
                                               const int* __restrict__ ofsA, const int* __restrict__ bktA,
                                               const int* __restrict__ ofsB, const int* __restrict__ bktB,
                                               const int* __restrict__ ofsS, const int* __restrict__ bktS,
                                               const float* __restrict__ gin_W, const float* __restrict__ gin_b,
                                               const float* __restrict__ gin_a,
                                               float* __restrict__ compOut, u16* __restrict__ sentOut){
  __shared__ __align__(16) char smem[52224];
  int tid = threadIdx.x;
  int wave = tid >> 6, lane = tid & 63;
  int b = blockIdx.x;
  if (b < NCC){
    // ---- company GIN ----
    float* Wat  = (float*)smem;            // 64*68
    float* Wbt  = Wat + 64 * 68;
    int*   eidx = (int*)(Wbt + 64 * 68);   // 2048
    float* part = (float*)(eidx + 2048);   // [16][2][64]
    float* xa   = part + 2048;
    float* xb   = xa + 64;
    float* outab = xb + 64;
    const float* Wa = gin_W + 0 * 4096;
    const float* Wb = gin_W + 1 * 4096;
    for (int i = tid; i < 4096; i += 1024){
      int j = i >> 6, k = i & 63;
      Wat[k * 68 + j] = Wa[i];
      Wbt[k * 68 + j] = Wb[i];
    }
    int c = b;
    float accA = 0.f, accB = 0.f;
    int a0 = ofsA[c], a1 = ofsA[c + 1];
    for (int base = a0; base < a1; base += 2048){
      int cnt = a1 - base; if (cnt > 2048) cnt = 2048;
      __syncthreads();
      for (int i = tid; i < cnt; i += 1024) eidx[i] = bktA[base + i];
      __syncthreads();
      #pragma unroll 4
      for (int i = wave; i < cnt; i += 16) accA += compIn[eidx[i] * 64 + lane];
    }
    int b0 = ofsB[c], b1 = ofsB[c + 1];
    for (int base = b0; base < b1; base += 2048){
      int cnt = b1 - base; if (cnt > 2048) cnt = 2048;
      __syncthreads();
      for (int i = tid; i < cnt; i += 1024) eidx[i] = bktB[base + i];
      __syncthreads();
      #pragma unroll 8
      for (int i = wave; i < cnt; i += 16) accB += bf2f(sentIn[(size_t)eidx[i] * 64 + lane]);
    }
    part[(wave * 2 + 0) * 64 + lane] = accA;
    part[(wave * 2 + 1) * 64 + lane] = accB;
    __syncthreads();
    if (tid < 128){
      int l = tid & 63, which = tid >> 6;
      float m = 0.f;
      #pragma unroll
      for (int w = 0; w < 16; ++w) m += part[(w * 2 + which) * 64 + l];
      float ci = compIn[c * 64 + l];
      if (which == 0) xa[l] = ci + m; else xb[l] = ci + m;
    }
    __syncthreads();
    if (tid < 128){
      int j = tid & 63;
      const float* X  = (tid < 64) ? xa : xb;
      const float* Wt = (tid < 64) ? Wat : Wbt;
      float acc = (tid < 64) ? gin_b[j] : gin_b[64 + j];
      #pragma unroll 4
      for (int k = 0; k < 64; ++k) acc += X[k] * Wt[k * 68 + j];
      float al = (tid < 64) ? gin_a[0] : gin_a[1];
      outab[tid] = (acc >= 0.f) ? acc : al * acc;
    }
    __syncthreads();
    if (tid < 64) compOut[c * 64 + tid] = outab[tid] + outab[64 + tid];
  } else {
    // ---- sentence GIN: 256 sentences/block, MFMA tail ----
    u16* sX   = (u16*)smem;        // [256][64] bf16 swizzled, 32 KB
    u16* sW   = sX + 16384;        // [64][64] bf16 swizzled, 8 KB
    int* eb   = (int*)(sW + 4096); // 2048
    int* sofs = eb + 2048;         // 257
    char* sXb = (char*)sX;
    char* sWb = (char*)sW;
    const float* W = gin_W + 2 * 4096;
    const float* bi = gin_b + 128;
    // stage W: thread -> n = tid>>4, k-quad q = tid&15
    {
      int n = tid >> 4, q = tid & 15;
      float4 v = *(const float4*)&W[n * 64 + q * 4];
      uint2 w;
      w.x = pk2(v.x, v.y); w.y = pk2(v.z, v.w);
      *(uint2*)(sWb + (((u32)(n * 128 + q * 8)) ^ ((u32)((n & 7) << 4)))) = w;
    }
    int sBase = (b - NCC) * 256;
    if (tid < 257){
      int idx = sBase + tid; if (idx > SSN) idx = SSN;
      sofs[tid] = ofsS[idx];
    }
    __syncthreads();
    int E0 = sofs[0];
    int tot = sofs[256] - E0;
    int staged = tot < 2048 ? tot : 2048;
    for (int i = tid; i < staged; i += 1024) eb[i] = bktS[E0 + i];
    __syncthreads();
    for (int q = 0; q < 16; ++q){
      int sL = wave * 16 + q;
      int s = sBase + sL;
      if (s < SSN){
        float acc = bf2f(sentIn[(size_t)s * 64 + lane]);
        int e0 = sofs[sL], e1 = sofs[sL + 1];
        for (int e = e0; e < e1; ++e){
          int r = e - E0;
          int src = (r < 2048) ? eb[r] : bktS[e];
          acc += compIn[src * 64 + lane];
        }
        *(u16*)(sXb + (((u32)(sL * 128 + lane * 2)) ^ ((u32)((sL & 7) << 4)))) = f2bf(acc);
      }
    }
    __syncthreads();
    int l15 = lane & 15, lg = lane >> 4;
    int arow = wave * 16 + l15;
    u32 ar_swz = (u32)((arow & 7) << 4);
    u32 br_swz = (u32)((l15 & 7) << 4);
    f32x4v acc4[4] = {};
    #pragma unroll
    for (int ks = 0; ks < 2; ++ks){
      short8 a0 = *(const short8*)(sXb + (((u32)(arow * 128 + ks * 64 + lg * 16)) ^ ar_swz));
      #pragma unroll
      for (int nt = 0; nt < 4; ++nt){
        short8 b0 = *(const short8*)(sWb + (((u32)((nt * 16 + l15) * 128 + ks * 64 + lg * 16)) ^ br_swz));
        acc4[nt] = __builtin_amdgcn_mfma_f32_16x16x32_bf16(a0, b0, acc4[nt], 0, 0, 0);
      }
    }
    float alpha = gin_a[2];
    #pragma unroll
    for (int nt = 0; nt < 4; ++nt){
      float bb = bi[nt * 16 + l15];
      #pragma unroll
      for (int j = 0; j < 4; ++j){
        int srow = sBase + wave * 16 + lg * 4 + j;
        if (srow < SSN){
          float h = acc4[nt][j] + bb;
          h = (h >= 0.f) ? h : alpha * h;
          sentOut[(size_t)srow * 64 + nt * 16 + l15] = f2bf(h);
        }
      }
    }
  }
}

// ---------------- company GIN layer 1 + fused classifier ----------------
__global__ __launch_bounds__(1024) void k_cgin1(const float* __restrict__ compIn, const u16* __restrict__ sentIn,
                                                const int* __restrict__ ofsA, const int* __restrict__ bktA,
                                                const int* __restrict__ ofsB, const int* __restrict__ bktB,
                                                const float* __restrict__ Wa, const float* __restrict__ ba, const float* aaP,
                                                const float* __restrict__ Wb, const float* __restrict__ bb, const float* abP,
                                                const float* __restrict__ clsW, const float* __restrict__ clsb,
                                                float* __restrict__ outp){
  __shared__ __align__(16) float Wat[64 * 68];
  __shared__ __align__(16) float Wbt[64 * 68];
  __shared__ int eidx[2048];
  __shared__ float part[16][2][64];
  __shared__ float xa[64], xb[64], outab[128];
  int tid = threadIdx.x;
  for (int i = tid; i < 4096; i += 1024){
    int j = i >> 6, k = i & 63;
    Wat[k * 68 + j] = Wa[i];
    Wbt[k * 68 + j] = Wb[i];
  }
  int wave = tid >> 6, lane = tid & 63;
  int c = blockIdx.x;
  float accA = 0.f, accB = 0.f;
  int a0 = ofsA[c], a1 = ofsA[c + 1];
  for (int base = a0; base < a1; base += 2048){
    int cnt = a1 - base; if (cnt > 2048) cnt = 2048;
    __syncthreads();
    for (int i = tid; i < cnt; i += 1024) eidx[i] = bktA[base + i];
    __syncthreads();
    #pragma unroll 4
    for (int i = wave; i < cnt; i += 16) accA += compIn[eidx[i] * 64 + lane];
  }
  int b0 = ofsB[c], b1 = ofsB[c + 1];
  for (int base = b0; base < b1; base += 2048){
    int cnt = b1 - base; if (cnt > 2048) cnt = 2048;
    __syncthreads();
    for (int i = tid; i < cnt; i += 1024) eidx[i] = bktB[base + i];
    __syncthreads();
    #pragma unroll 8
    for (int i = wave; i < cnt; i += 16) accB += bf2f(sentIn[(size_t)eidx[i] * 64 + lane]);
  }
  part[wave][0][lane] = accA;
  part[wave][1][lane] = accB;
  __syncthreads();
  if (tid < 128){
    int l = tid & 63, which = tid >> 6;
    float m = 0.f;
    #pragma unroll
    for (int w = 0; w < 16; ++w) m += part[w][which][l];
    float ci = compIn[c * 64 + l];
    if (which == 0) xa[l] = ci + m; else xb[l] = ci + m;
  }
  __syncthreads();
  if (tid < 128){
    int j = tid & 63;
    const float* X  = (tid < 64) ? xa : xb;
    const float* Wt = (tid < 64) ? Wat : Wbt;
    float acc = (tid < 64) ? ba[j] : bb[j];
    #pragma unroll 4
    for (int k = 0; k < 64; ++k) acc += X[k] * Wt[k * 68 + j];
    float al = (tid < 64) ? *aaP : *abP;
    outab[tid] = (acc >= 0.f) ? acc : al * acc;
  }
  __syncthreads();
  if (tid < 64) xa[tid] = outab[tid] + outab[64 + tid];
  __syncthreads();
  if (tid < 128){
    int j = tid >> 6;
    float p = xa[lane] * clsW[j * 64 + lane];
    #pragma unroll
    for (int s = 32; s > 0; s >>= 1) p += __shfl_down(p, s, 64);
    if (lane == 0) outp[c * 2 + j] = p + clsb[j];
  }
}

extern "C" void kernel_launch(void* const* d_in, const int* in_sizes, int n_in,
                              void* d_out, int out_size, void* d_ws, size_t ws_size,
                              hipStream_t stream) {
  (void)in_sizes; (void)n_in; (void)out_size; (void)ws_size;
  const float* company_ts = (const float*)d_in[0];
  const float* sentence_x = (const float*)d_in[1];
  const int*   company_ids = (const int*)d_in[2];
  const int*   c2c_src = (const int*)d_in[3];
  const int*   c2c_dst = (const int*)d_in[4];
  const int*   s2c_src = (const int*)d_in[5];
  const int*   s2c_dst = (const int*)d_in[6];
  const int*   c2s_src = (const int*)d_in[7];
  const int*   c2s_dst = (const int*)d_in[8];
  const float* bn_gamma = (const float*)d_in[9];
  const float* bn_beta  = (const float*)d_in[10];
  const float* Wih0 = (const float*)d_in[11];
  const float* Whh0 = (const float*)d_in[12];
  const float* bih0 = (const float*)d_in[13];
  const float* bhh0 = (const float*)d_in[14];
  const float* Wih1 = (const float*)d_in[15];
  const float* Whh1 = (const float*)d_in[16];
  const float* bih1 = (const float*)d_in[17];
  const float* bhh1 = (const float*)d_in[18];
  const float* fc_W = (const float*)d_in[19];
  const float* fc_b = (const float*)d_in[20];
  const float* comp_emb = (const float*)d_in[21];
  const float* proj_W = (const float*)d_in[22];
  const float* proj_b = (const float*)d_in[23];
  const float* gin_W = (const float*)d_in[24];
  const float* gin_b = (const float*)d_in[25];
  const float* gin_a = (const float*)d_in[26];
  const float* cls_W = (const float*)d_in[27];
  const float* cls_b = (const float*)d_in[28];
  float* outp = (float*)d_out;

  char* ws = (char*)d_ws;
  size_t off = 0;
  auto alloc = [&](size_t bytes)->char* {
    char* r = ws + off;
    off += (bytes + 255) & ~(size_t)255;
    return r;
  };
  float* ts_norm = (float*)alloc((size_t)NCC * TTT * 4);
  float* comp0   = (float*)alloc((size_t)NCC * 64 * 4);
  float* comp1   = (float*)alloc((size_t)NCC * 64 * 4);
  u16*   sent0   = (u16*)alloc((size_t)SSN * 64 * 2);
  u16*   sent1   = (u16*)alloc((size_t)SSN * 64 * 2);
  int*   blockHist = (int*)alloc((size_t)NCC * NB2 * 4);
  int*   colTotal  = (int*)alloc((size_t)NCC * 4);
  int*   cnt_c2c  = (int*)alloc((size_t)ZN * 4);
  int*   cnt2_c2c = cnt_c2c + NCC;
  int*   cnt_c2s  = cnt2_c2c + NCC;
  int*   cnt2_c2s = cnt_c2s + SSN;
  int*   off_c2c = (int*)alloc((size_t)(NCC + 1) * 4);
  int*   off_s2c = (int*)alloc((size_t)(NCC + 1) * 4);
  int*   off_c2s = (int*)alloc((size_t)(SSN + 1) * 4);
  int*   bkt_c2c = (int*)alloc((size_t)ECN * 4);
  int*   bkt_s2c = (int*)alloc((size_t)EEN * 4);
  int*   bkt_c2s = (int*)alloc((size_t)EEN * 4);
  int*   bsum    = (int*)alloc(256 * 4);

  // --- CSR builds + bn ---
  k_zero<<<(ZN + 255) / 256, 256, 0, stream>>>(cnt_c2c, ZN);
  k_histF<<<NB2 + HALLB, 256, 0, stream>>>(s2c_dst, blockHist, c2c_dst, cnt_c2c, c2s_dst, cnt_c2s);
  k_scanA<<<NCC + CSBLK + TTT, 1024, 0, stream>>>(blockHist, colTotal, cnt_c2s, off_c2s, bsum,
                                                  company_ts, bn_gamma, bn_beta, ts_norm);
  k_scanB<<<1 + CSBLK, 1024, 0, stream>>>(cnt_c2c, off_c2c, colTotal, off_s2c, off_c2s, bsum);
  k_scatF<<<NB2 + HALLB, 256, 0, stream>>>(s2c_src, s2c_dst, blockHist, off_s2c, bkt_s2c,
                                           c2c_src, c2c_dst, off_c2c, cnt2_c2c, bkt_c2c,
                                           c2s_src, c2s_dst, off_c2s, cnt2_c2s, bkt_c2s);

  // --- time-series branch ---
  k_lstm01<<<(NCC + 3) / 4, 256, 0, stream>>>(ts_norm, Wih0, Whh0, bih0, bhh0,
                                              Wih1, Whh1, bih1, bhh1,
                                              fc_W, fc_b, comp_emb, company_ids, comp0);

  // --- sentence projection (MFMA) ---
  k_projm<<<(SSN + 127) / 128, 256, 0, stream>>>(sentence_x, proj_W, proj_b, sent0);

  // --- GIN layer 0: company + sentence merged (sent0 -> sent1, comp0 -> comp1) ---
  k_gin0<<<NCC + SGB, 1024, 0, stream>>>(comp0, sent0,
                                         off_c2c, bkt_c2c, off_s2c, bkt_s2c,
                                         off_c2s, bkt_c2s,
                                         gin_W, gin_b, gin_a,
                                         comp1, sent1);

  // --- GIN layer 1 + classifier (layer-1 new_sent is dead code) ---
  k_cgin1<<<NCC, 1024, 0, stream>>>(comp1, sent1,
                                    off_c2c, bkt_c2c, off_s2c, bkt_s2c,
                                    gin_W + 3 * 4096, gin_b + 3 * 64, gin_a + 3,
                                    gin_W + 4 * 4096, gin_b + 4 * 64, gin_a + 4,
                                    cls_W, cls_b, outp);
}